// Round 7
// baseline (241.127 us; speedup 1.0000x reference)
//
#include <hip/hip_runtime.h>
#include <math.h>

#define NEGF  (-1e30f)
#define BIGF  (1000000.0f)
#define SCALE_ (0.08838834764831845f)   // 1/sqrt(128)
#define L2INV_ (0.20762050593046014f)   // log2(10000)/64

typedef __attribute__((ext_vector_type(4))) float f32x4;
typedef __attribute__((ext_vector_type(8))) short short8;
typedef __attribute__((ext_vector_type(4))) short short4v;
typedef __attribute__((ext_vector_type(8))) _Float16 half8;

#define GLDS16(gp, lp) __builtin_amdgcn_global_load_lds( \
    (const __attribute__((address_space(1))) void*)(gp), \
    (__attribute__((address_space(3))) void*)(lp), 16, 0, 0)

__device__ __forceinline__ float wave_max(float v) {
    #pragma unroll
    for (int off = 32; off >= 1; off >>= 1) v = fmaxf(v, __shfl_xor(v, off, 64));
    return v;
}
__device__ __forceinline__ float wave_sum(float v) {
    #pragma unroll
    for (int off = 32; off >= 1; off >>= 1) v += __shfl_xor(v, off, 64);
    return v;
}
__device__ __forceinline__ short bf16_of(float f) {
    union { float f; unsigned u; } x; x.f = f;
    unsigned r = x.u + 0x7fffu + ((x.u >> 16) & 1u);
    return (short)(r >> 16);
}
__device__ __forceinline__ short f16_of(float f) {
    _Float16 h = (_Float16)f;
    union { _Float16 h; short s; } u; u.h = h;
    return u.s;
}
__device__ __forceinline__ float f32_of_f16(short s) {
    union { _Float16 h; short s; } u; u.s = s;
    return (float)u.h;
}

// -------- Kernel 0a: x (fp32) -> xhi/xlo fp16 split ------------------------
__global__ __launch_bounds__(256) void xconv_kernel(
    const float* __restrict__ x, short* __restrict__ xhi, short* __restrict__ xlo)
{
    const int i = blockIdx.x * 1024 + threadIdx.x * 4;
    float4 f = *(const float4*)(x + i);
    short4v hi, lo;
    float fv[4] = {f.x, f.y, f.z, f.w};
    #pragma unroll
    for (int c = 0; c < 4; ++c) {
        short h = f16_of(fv[c]);
        hi[c] = h;
        lo[c] = f16_of(fv[c] - f32_of_f16(h));
    }
    *(short4v*)(xhi + i) = hi;
    *(short4v*)(xlo + i) = lo;
}

// -------- Kernel 0b: W's -> WT fp16 split, transposed [1600][1024] ---------
__global__ __launch_bounds__(256) void wconv_kernel(
    const float* __restrict__ Wq, const float* __restrict__ Wk,
    const float* __restrict__ Wv, const float* __restrict__ Wg,
    short* __restrict__ wthi, short* __restrict__ wtlo)
{
    __shared__ float tile[32][33];
    const int ct = blockIdx.x, kt = blockIdx.y;
    const int c = threadIdx.x & 31, r0 = threadIdx.x >> 5;
    #pragma unroll
    for (int rr = 0; rr < 32; rr += 8) {
        int k = kt * 32 + r0 + rr;
        int gc = ct * 32 + c;
        float val;
        if (gc < 1024)      val = Wq[k * 1024 + gc];
        else if (gc < 1280) val = Wk[k * 256 + gc - 1024];
        else if (gc < 1536) val = Wv[k * 256 + gc - 1280];
        else if (gc < 1560) val = Wg[k * 24 + gc - 1536];
        else                val = 0.f;
        tile[r0 + rr][c] = val;
    }
    __syncthreads();
    #pragma unroll
    for (int rr = 0; rr < 32; rr += 8) {
        int col = ct * 32 + r0 + rr;
        int k = kt * 32 + c;
        float val = tile[c][r0 + rr];
        short hi = f16_of(val);
        short lo = f16_of(val - f32_of_f16(hi));
        wthi[(size_t)col * 1024 + k] = hi;
        wtlo[(size_t)col * 1024 + k] = lo;
    }
}

// -------- Kernel 1: projections via split-fp16 MFMA, LDS-staged ------------
__global__ __launch_bounds__(512) void proj_mfma_kernel(
    const short* __restrict__ xhi, const short* __restrict__ xlo,
    const short* __restrict__ wthi, const short* __restrict__ wtlo,
    float* __restrict__ q, float* __restrict__ k_raw,
    float* __restrict__ v, float* __restrict__ gsig)
{
    __shared__ __align__(16) short lds[24576];
    const int cb = blockIdx.x;
    const int tb = blockIdx.y;
    const int w = threadIdx.x >> 6;
    const int l = threadIdx.x & 63;
    const int l16 = l & 15, g4 = l >> 4;
    const int wm = w >> 1, wn = w & 1;
    const int row0 = tb * 128, col0 = cb * 64;

    const short* pAhi[2]; const short* pAlo[2];
    #pragma unroll
    for (int j = 0; j < 2; ++j) {
        int b = (2 * w + j) * 1024 + l * 16;
        int row = b >> 7;
        int kb = (b & 127) ^ ((row & 7) << 4);
        pAhi[j] = xhi + (size_t)(row0 + row) * 1024 + (kb >> 1);
        pAlo[j] = xlo + (size_t)(row0 + row) * 1024 + (kb >> 1);
    }
    const short* pBhi; const short* pBlo;
    {
        int b = w * 1024 + l * 16;
        int col = b >> 7;
        int kb = (b & 127) ^ ((col & 7) << 4);
        pBhi = wthi + (size_t)(col0 + col) * 1024 + (kb >> 1);
        pBlo = wtlo + (size_t)(col0 + col) * 1024 + (kb >> 1);
    }

    f32x4 acc[2][2];
    #pragma unroll
    for (int mt = 0; mt < 2; ++mt)
        #pragma unroll
        for (int nt = 0; nt < 2; ++nt) acc[mt][nt] = (f32x4)0.f;

    for (int k0 = 0; k0 < 1024; k0 += 64) {
        GLDS16(pAhi[0] + k0, &lds[(2 * w + 0) * 512]);
        GLDS16(pAhi[1] + k0, &lds[(2 * w + 1) * 512]);
        GLDS16(pAlo[0] + k0, &lds[8192 + (2 * w + 0) * 512]);
        GLDS16(pAlo[1] + k0, &lds[8192 + (2 * w + 1) * 512]);
        GLDS16(pBhi + k0,    &lds[16384 + w * 512]);
        GLDS16(pBlo + k0,    &lds[20480 + w * 512]);
        __syncthreads();
        #pragma unroll
        for (int ksub = 0; ksub < 2; ++ksub) {
            half8 ah[2], al[2], bh[2], bl[2];
            #pragma unroll
            for (int mt = 0; mt < 2; ++mt) {
                int row = wm * 32 + mt * 16 + l16;
                int kb = (ksub * 64 + g4 * 16) ^ ((row & 7) << 4);
                ah[mt] = *(const half8*)(const void*)&lds[row * 64 + (kb >> 1)];
                al[mt] = *(const half8*)(const void*)&lds[8192 + row * 64 + (kb >> 1)];
            }
            #pragma unroll
            for (int nt = 0; nt < 2; ++nt) {
                int col = wn * 32 + nt * 16 + l16;
                int kb = (ksub * 64 + g4 * 16) ^ ((col & 7) << 4);
                bh[nt] = *(const half8*)(const void*)&lds[16384 + col * 64 + (kb >> 1)];
                bl[nt] = *(const half8*)(const void*)&lds[20480 + col * 64 + (kb >> 1)];
            }
            #pragma unroll
            for (int mt = 0; mt < 2; ++mt)
                #pragma unroll
                for (int nt = 0; nt < 2; ++nt) {
                    acc[mt][nt] = __builtin_amdgcn_mfma_f32_16x16x32_f16(ah[mt], bh[nt], acc[mt][nt], 0, 0, 0);
                    acc[mt][nt] = __builtin_amdgcn_mfma_f32_16x16x32_f16(ah[mt], bl[nt], acc[mt][nt], 0, 0, 0);
                    acc[mt][nt] = __builtin_amdgcn_mfma_f32_16x16x32_f16(al[mt], bh[nt], acc[mt][nt], 0, 0, 0);
                }
        }
        __syncthreads();
    }
    #pragma unroll
    for (int mt = 0; mt < 2; ++mt) {
        #pragma unroll
        for (int r = 0; r < 4; ++r) {
            const int tt = row0 + wm * 32 + mt * 16 + g4 * 4 + r;
            #pragma unroll
            for (int nt = 0; nt < 2; ++nt) {
                const int cg = col0 + wn * 32 + nt * 16 + l16;
                const float val = acc[mt][nt][r];
                if (cg < 1024)      q[(size_t)tt * 1024 + cg] = val;
                else if (cg < 1280) k_raw[(size_t)tt * 256 + cg - 1024] = val;
                else if (cg < 1536) v[(size_t)tt * 256 + cg - 1280] = val;
                else if (cg < 1560) gsig[(size_t)tt * 24 + cg - 1536] = 1.0f / (1.0f + expf(-val));
            }
        }
    }
}

// ------ Kernel 2: RoPE on q (in place) and k, plus bf16 copies -------------
__global__ __launch_bounds__(256) void rope_conv_kernel(
    float* __restrict__ q, const float* __restrict__ k_raw,
    short* __restrict__ qb, short* __restrict__ krb)
{
    const int t = blockIdx.x * 4 + (threadIdx.x >> 6);
    const int h = blockIdx.y;
    const int i = threadIdx.x & 63;
    float inv = exp2f(-(float)i * L2INV_);
    float ang = (float)t * inv;
    float sn, cs;
    sincosf(ang, &sn, &cs);
    if (h < 8) {
        float* p = q + t * 1024 + h * 128;
        float x1 = p[i], x2 = p[i + 64];
        float r1 = x1 * cs - x2 * sn;
        float r2 = x1 * sn + x2 * cs;
        p[i] = r1; p[i + 64] = r2;
        qb[t * 1024 + h * 128 + i]      = bf16_of(r1);
        qb[t * 1024 + h * 128 + i + 64] = bf16_of(r2);
    } else {
        const float* s = k_raw + t * 256 + (h - 8) * 128;
        float x1 = s[i], x2 = s[i + 64];
        krb[t * 256 + (h - 8) * 128 + i]      = bf16_of(x1 * cs - x2 * sn);
        krb[t * 256 + (h - 8) * 128 + i + 64] = bf16_of(x1 * sn + x2 * cs);
    }
}

// ------ Kernel 2b: v (fp32 [s][kv][d]) -> vT bf16 [kv][d][s] ---------------
__global__ __launch_bounds__(256) void vtrans_kernel(
    const float* __restrict__ v, short* __restrict__ vT)
{
    __shared__ short tile[32][33];
    const int s0 = blockIdx.x * 32, d0 = blockIdx.y * 32, kv = blockIdx.z;
    const int c = threadIdx.x & 31, r0 = threadIdx.x >> 5;
    #pragma unroll
    for (int rr = 0; rr < 32; rr += 8) {
        int r = r0 + rr;
        tile[r][c] = bf16_of(v[((size_t)(s0 + r) * 2 + kv) * 128 + d0 + c]);
    }
    __syncthreads();
    #pragma unroll
    for (int rr = 0; rr < 32; rr += 8) {
        int r = r0 + rr;
        vT[((size_t)kv * 128 + d0 + r) * 2048 + s0 + c] = tile[c][r];
    }
}

// ------- Kernel 3: pooled k_cmp (roped at j*32) and v_cmp ------------------
__global__ __launch_bounds__(256) void pool_kernel(
    const float* __restrict__ k_raw, const float* __restrict__ v_raw,
    const float* __restrict__ wk_pool, const float* __restrict__ wv_pool,
    const float* __restrict__ pe, float* __restrict__ k_cmp, float* __restrict__ v_cmp)
{
    const int j = blockIdx.x;
    const int tid = threadIdx.x;
    const int kv = tid >> 7, d = tid & 127;
    float ak = 0.f, av = 0.f;
    for (int s = 0; s < 32; ++s) {
        float pev = pe[(kv * 32 + s) * 128 + d];
        float kk = k_raw[((j * 32 + s) * 2 + kv) * 128 + d] + pev;
        float vv = v_raw[((j * 32 + s) * 2 + kv) * 128 + d] + pev;
        ak += kk * wk_pool[kv * 32 + s];
        av += vv * wv_pool[kv * 32 + s];
    }
    __shared__ float sk[256];
    sk[tid] = ak;
    __syncthreads();
    int i = d & 63;
    float inv = exp2f(-(float)i * L2INV_);
    float ang = (float)(j * 32) * inv;
    float sn, cs; sincosf(ang, &sn, &cs);
    float x1 = sk[kv * 128 + i], x2 = sk[kv * 128 + i + 64];
    float outv = (d < 64) ? (x1 * cs - x2 * sn) : (x1 * sn + x2 * cs);
    k_cmp[(j * 2 + kv) * 128 + d] = outv;
    v_cmp[(j * 2 + kv) * 128 + d] = av;
}

// ------- Kernel 4: compressed attention + pw + top-8 selection (fp32) ------
__global__ __launch_bounds__(64) void cmp_sel_kernel(
    const float* __restrict__ q, const float* __restrict__ k_cmp,
    const float* __restrict__ v_cmp, float* __restrict__ o_cmp,
    unsigned long long* __restrict__ sel_mask)
{
    const int t = blockIdx.x;
    const int kv = blockIdx.y;
    const int lane = threadIdx.x;
    __shared__ float qs[4][128];
    __shared__ float ps[64];
    for (int idx = lane; idx < 512; idx += 64)
        qs[idx >> 7][idx & 127] = q[t * 1024 + kv * 512 + idx];
    __syncthreads();
    const int j = lane;
    const float4* krow = (const float4*)&k_cmp[(j * 2 + kv) * 128];
    const bool vis = (t >= j * 32 + 31);
    const bool anyvis = (t >= 31);
    float pw = 0.f;
    for (int g = 0; g < 4; ++g) {
        const float4* qrow = (const float4*)qs[g];
        float s = 0.f;
        #pragma unroll 8
        for (int ii = 0; ii < 32; ++ii) {
            float4 kk = krow[ii], qq = qrow[ii];
            s += kk.x * qq.x + kk.y * qq.y + kk.z * qq.z + kk.w * qq.w;
        }
        s *= SCALE_;
        s = vis ? s : NEGF;
        float m = wave_max(s);
        float e = expf(s - m);
        float sum = wave_sum(e);
        float p = anyvis ? (e / sum) : 0.f;
        pw += p;
        ps[lane] = p;
        __syncthreads();
        float o0 = 0.f, o1 = 0.f;
        for (int jj = 0; jj < 64; ++jj) {
            float pp = ps[jj];
            o0 += pp * v_cmp[(jj * 2 + kv) * 128 + lane];
            o1 += pp * v_cmp[(jj * 2 + kv) * 128 + lane + 64];
        }
        o_cmp[t * 1024 + kv * 512 + g * 128 + lane]      = o0;
        o_cmp[t * 1024 + kv * 512 + g * 128 + lane + 64] = o1;
        __syncthreads();
    }
    const int cur = t >> 5;
    const int curm1 = cur > 0 ? cur - 1 : 0;
    const bool forced = (j == 0) || (j == cur) || (j == curm1);
    const bool allowed = (j * 32 <= t);
    float sc = allowed ? (pw + (forced ? BIGF : 0.f)) : -1.0f;
    unsigned long long selm = 0ull;
    for (int it = 0; it < 8; ++it) {
        float bv = sc; int bi = j;
        #pragma unroll
        for (int off = 32; off >= 1; off >>= 1) {
            float ov = __shfl_xor(bv, off, 64);
            int   oi = __shfl_xor(bi, off, 64);
            if (ov > bv || (ov == bv && oi < bi)) { bv = ov; bi = oi; }
        }
        if (bv > -0.5f) selm |= (1ull << bi);
        if (j == bi) sc = -3e38f;
    }
    if (lane == 0) sel_mask[t * 2 + kv] = selm;
}

// ------- Kernel 5: fused slc+swa, wave-pair work split + flash merge -------
// block = (16-query tile, kv), 8 waves. Pair (w, w+4) shares g=w&3:
// half = w>>2. Phase 1: slc blocks bi%2==half; merge. Phase 2: swa chunks
// ci%2==half; merge. Swapped-operand QK^T (per-lane softmax) throughout.
__global__ __launch_bounds__(512) void slcswa_kernel(
    const short* __restrict__ qb, const short* __restrict__ krb,
    const short* __restrict__ vT, const unsigned long long* __restrict__ sel,
    const float* __restrict__ gsig, const float* __restrict__ o_cmp,
    float* __restrict__ out)
{
    const int t0 = blockIdx.x * 16;
    const int kv = blockIdx.y;
    const int w  = threadIdx.x >> 6;       // 0..7
    const int l  = threadIdx.x & 63;
    const int l16 = l & 15, g4 = l >> 4;
    const int g  = w & 3;
    const int half = w >> 2;               // 0 = merger (A), 1 = partial (B)
    __shared__ __align__(16) short plds[8][16][40];
    __shared__ float o_slc[4][16][132];
    __shared__ float o_swa[4][16][132];
    __shared__ float mBp[4][16], lBp[4][16];
    __shared__ float gl[16][12];
    __shared__ unsigned long long qm[16];
    __shared__ unsigned char blist[64];
    __shared__ int nbs;
    if (threadIdx.x < 16) qm[threadIdx.x] = sel[(size_t)(t0 + threadIdx.x) * 2 + kv];
    if (threadIdx.x >= 64 && threadIdx.x < 256) {
        int idx = threadIdx.x - 64;
        gl[idx / 12][idx % 12] = gsig[(size_t)(t0 + idx / 12) * 24 + kv * 12 + idx % 12];
    }
    __syncthreads();
    if (threadIdx.x == 0) {
        unsigned long long u = 0ull;
        #pragma unroll
        for (int i = 0; i < 16; ++i) u |= qm[i];
        int n = 0;
        while (u) { blist[n++] = (unsigned char)(__ffsll((long long)u) - 1); u &= u - 1; }
        nbs = n;
    }
    __syncthreads();

    // Q fragment (B-operand: cols = queries)
    short8 qf[4];
    #pragma unroll
    for (int ks = 0; ks < 4; ++ks)
        qf[ks] = *(const short8*)(qb + ((size_t)(t0 + l16) * 8 + kv * 4 + g) * 128 + ks * 32 + g4 * 8);
    const int tq = t0 + l16;

    // ================= phase 1: selected =================
    {
        f32x4 acc[8];
        #pragma unroll
        for (int dt = 0; dt < 8; ++dt) acc[dt] = (f32x4)0.f;
        float m_r = NEGF, l_r = 0.f;
        const unsigned long long myqm = qm[l16];
        const int nb = nbs;
        if (half < nb) {
            int j = blist[half];
            short8 kfC[2][4];
            #pragma unroll
            for (int nt = 0; nt < 2; ++nt)
                #pragma unroll
                for (int ks = 0; ks < 4; ++ks)
                    kfC[nt][ks] = *(const short8*)(krb + ((size_t)(j * 32 + nt * 16 + l16) * 2 + kv) * 128 + ks * 32 + g4 * 8);
            for (int bi = half; bi < nb; bi += 2) {
                const int s0 = j * 32;
                const int jn = (bi + 2 < nb) ? blist[bi + 2] : j;
                short8 kfN[2][4];                 // prefetch next item's K tile
                #pragma unroll
                for (int nt = 0; nt < 2; ++nt)
                    #pragma unroll
                    for (int ks = 0; ks < 4; ++ks)
                        kfN[nt][ks] = *(const short8*)(krb + ((size_t)(jn * 32 + nt * 16 + l16) * 2 + kv) * 128 + ks * 32 + g4 * 8);
                f32x4 sct[2];
                sct[0] = (f32x4)0.f; sct[1] = (f32x4)0.f;
                #pragma unroll
                for (int ks = 0; ks < 4; ++ks) {
                    sct[0] = __builtin_amdgcn_mfma_f32_16x16x32_bf16(kfC[0][ks], qf[ks], sct[0], 0, 0, 0);
                    sct[1] = __builtin_amdgcn_mfma_f32_16x16x32_bf16(kfC[1][ks], qf[ks], sct[1], 0, 0, 0);
                }
                const bool inm = (myqm >> j) & 1ull;
                float p[8];
                float mx = NEGF;
                #pragma unroll
                for (int nt = 0; nt < 2; ++nt)
                    #pragma unroll
                    for (int r = 0; r < 4; ++r) {
                        const int key = s0 + nt * 16 + g4 * 4 + r;
                        const bool vv = inm && (key <= tq);
                        const float sv = vv ? sct[nt][r] * SCALE_ : NEGF;
                        p[nt * 4 + r] = sv;
                        mx = fmaxf(mx, sv);
                    }
                mx = fmaxf(mx, __shfl_xor(mx, 16, 64));
                mx = fmaxf(mx, __shfl_xor(mx, 32, 64));
                const float mnew = fmaxf(m_r, mx);
                const float alx = __expf(m_r - mnew);
                float rs = 0.f;
                #pragma unroll
                for (int i = 0; i < 8; ++i) { float pv = __expf(p[i] - mnew); p[i] = pv; rs += pv; }
                rs += __shfl_xor(rs, 16, 64);
                rs += __shfl_xor(rs, 32, 64);
                l_r = l_r * alx + rs;
                m_r = mnew;
                #pragma unroll
                for (int dt = 0; dt < 8; ++dt) acc[dt] *= alx;
                short4v pk0, pk1;
                #pragma unroll
                for (int r = 0; r < 4; ++r) { pk0[r] = bf16_of(p[r]); pk1[r] = bf16_of(p[4 + r]); }
                *(short4v*)&plds[w][l16][g4 * 4]      = pk0;
                *(short4v*)&plds[w][l16][16 + g4 * 4] = pk1;
                short8 pa = *(const short8*)(&plds[w][l16][g4 * 8]);
                #pragma unroll
                for (int dt = 0; dt < 8; ++dt) {
                    short8 vf = *(const short8*)(vT + ((size_t)kv * 128 + dt * 16 + l16) * 2048 + s0 + g4 * 8);
                    acc[dt] = __builtin_amdgcn_mfma_f32_16x16x32_bf16(vf, pa, acc[dt], 0, 0, 0);
                }
                j = jn;
                #pragma unroll
                for (int nt = 0; nt < 2; ++nt)
                    #pragma unroll
                    for (int ks = 0; ks < 4; ++ks) kfC[nt][ks] = kfN[nt][ks];
            }
        }
        if (half == 1) {
            if (g4 == 0) { mBp[g][l16] = m_r; lBp[g][l16] = l_r; }
            #pragma unroll
            for (int dt = 0; dt < 8; ++dt)
                #pragma unroll
                for (int r = 0; r < 4; ++r)
                    o_slc[g][l16][dt * 16 + g4 * 4 + r] = acc[dt][r];
        }
        __syncthreads();
        if (half == 0) {
            const float mBv = mBp[g][l16], lBv = lBp[g][l16];
            const float mm = fmaxf(m_r, mBv);
            const float aA = __expf(m_r - mm);
            const float aB = __expf(mBv - mm);
            const float rl = 1.0f / (l_r * aA + lBv * aB);
            #pragma unroll
            for (int dt = 0; dt < 8; ++dt)
                #pragma unroll
                for (int r = 0; r < 4; ++r) {
                    const int idx = dt * 16 + g4 * 4 + r;
                    o_slc[g][l16][idx] = (acc[dt][r] * aA + o_slc[g][l16][idx] * aB) * rl;
                }
        }
    }
    __syncthreads();
    // ================= phase 2: sliding window =================
    {
        f32x4 acc[8];
        #pragma unroll
        for (int dt = 0; dt < 8; ++dt) acc[dt] = (f32x4)0.f;
        float m_r = NEGF, l_r = 0.f;
        const int sLo = (t0 >= 256) ? (t0 - 256) : 0;
        for (int s0 = sLo + half * 32; s0 <= t0 + 15; s0 += 64) {
            f32x4 sct[2];
            sct[0] = (f32x4)0.f; sct[1] = (f32x4)0.f;
            #pragma unroll
            for (int nt = 0; nt < 2; ++nt) {
                short8 kf[4];
                int sr = s0 + nt * 16 + l16;
                if (sr > 2047) sr = 2047;          // clamp; masked below
                #pragma unroll
                for (int ks = 0; ks < 4; ++ks)
                    kf[ks] = *(const short8*)(krb + ((size_t)sr * 2 + kv) * 128 + ks * 32 + g4 * 8);
                #pragma unroll
                for (int ks = 0; ks < 4; ++ks)
                    sct[nt] = __builtin_amdgcn_mfma_f32_16x16x32_bf16(kf[ks], qf[ks], sct[nt], 0, 0, 0);
            }
            float p[8];
            float mx = NEGF;
            #pragma unroll
            for (int nt = 0; nt < 2; ++nt)
                #pragma unroll
                for (int r = 0; r < 4; ++r) {
                    const int key = s0 + nt * 16 + g4 * 4 + r;
                    const bool vv = (key <= tq) && (key >= tq - 256);
                    const float sv = vv ? sct[nt][r] * SCALE_ : NEGF;
                    p[nt * 4 + r] = sv;
                    mx = fmaxf(mx, sv);
                }
            mx = fmaxf(mx, __shfl_xor(mx, 16, 64));
            mx = fmaxf(mx, __shfl_xor(mx, 32, 64));
            const float mnew = fmaxf(m_r, mx);
            const float alx = __expf(m_r - mnew);
            float rs = 0.f;
            #pragma unroll
            for (int i = 0; i < 8; ++i) { float pv = __expf(p[i] - mnew); p[i] = pv; rs += pv; }
            rs += __shfl_xor(rs, 16, 64);
            rs += __shfl_xor(rs, 32, 64);
            l_r = l_r * alx + rs;
            m_r = mnew;
            #pragma unroll
            for (int dt = 0; dt < 8; ++dt) acc[dt] *= alx;
            short4v pk0, pk1;
            #pragma unroll
            for (int r = 0; r < 4; ++r) { pk0[r] = bf16_of(p[r]); pk1[r] = bf16_of(p[4 + r]); }
            *(short4v*)&plds[w][l16][g4 * 4]      = pk0;
            *(short4v*)&plds[w][l16][16 + g4 * 4] = pk1;
            short8 pa = *(const short8*)(&plds[w][l16][g4 * 8]);
            int sc0 = s0 + g4 * 8;
            if (sc0 > 2040) sc0 = 2040;            // clamp; those p's are 0
            #pragma unroll
            for (int dt = 0; dt < 8; ++dt) {
                short8 vf = *(const short8*)(vT + ((size_t)kv * 128 + dt * 16 + l16) * 2048 + sc0);
                acc[dt] = __builtin_amdgcn_mfma_f32_16x16x32_bf16(vf, pa, acc[dt], 0, 0, 0);
            }
        }
        if (half == 1) {
            if (g4 == 0) { mBp[g][l16] = m_r; lBp[g][l16] = l_r; }
            #pragma unroll
            for (int dt = 0; dt < 8; ++dt)
                #pragma unroll
                for (int r = 0; r < 4; ++r)
                    o_swa[g][l16][dt * 16 + g4 * 4 + r] = acc[dt][r];
        }
        __syncthreads();
        if (half == 0) {
            const float mBv = mBp[g][l16], lBv = lBp[g][l16];
            const float mm = fmaxf(m_r, mBv);
            const float aA = __expf(m_r - mm);
            const float aB = __expf(mBv - mm);
            const float rl = 1.0f / (l_r * aA + lBv * aB);
            #pragma unroll
            for (int dt = 0; dt < 8; ++dt)
                #pragma unroll
                for (int r = 0; r < 4; ++r) {
                    const int idx = dt * 16 + g4 * 4 + r;
                    o_swa[g][l16][idx] = (acc[dt][r] * aA + o_swa[g][l16][idx] * aB) * rl;
                }
        }
    }
    __syncthreads();
    // ---------------- gated combine (coalesced, all 512 threads) -----------
    for (int idx = threadIdx.x; idx < 8192; idx += 512) {
        const int qq = idx >> 9, c = idx & 511;
        const int gg = c >> 7, d = c & 127;
        const size_t oidx = (size_t)(t0 + qq) * 1024 + kv * 512 + c;
        out[oidx] = gl[qq][gg * 3 + 0] * o_cmp[oidx]
                  + gl[qq][gg * 3 + 1] * o_slc[gg][qq][d]
                  + gl[qq][gg * 3 + 2] * o_swa[gg][qq][d];
    }
}

extern "C" void kernel_launch(void* const* d_in, const int* in_sizes, int n_in,
                              void* d_out, int out_size, void* d_ws, size_t ws_size,
                              hipStream_t stream)
{
    const float* x       = (const float*)d_in[0];
    const float* Wq      = (const float*)d_in[1];
    const float* Wk      = (const float*)d_in[2];
    const float* Wv      = (const float*)d_in[3];
    const float* Wg      = (const float*)d_in[4];
    const float* wk_pool = (const float*)d_in[5];
    const float* wv_pool = (const float*)d_in[6];
    const float* pe      = (const float*)d_in[7];
    float* out = (float*)d_out;
    float* ws  = (float*)d_ws;

    float* q     = ws;                         // 2,097,152
    float* k_raw = q + 2097152;                //   524,288
    float* v     = k_raw + 524288;             //   524,288
    float* gsig  = v + 524288;                 //    49,152
    float* k_cmp = gsig + 49152;               //    16,384
    float* v_cmp = k_cmp + 16384;              //    16,384
    unsigned long long* sel = (unsigned long long*)(v_cmp + 16384); // 8,192 f
    float* o_cmp = (float*)sel + 8192;         // 2,097,152
    short* xhi   = (short*)o_cmp;              // aliases o_cmp (dead before cmp_sel)
    short* xlo   = xhi + 2097152;
    short* qb    = (short*)(o_cmp + 2097152);  // 2,097,152 shorts
    short* krb   = qb + 2097152;               //   524,288 shorts
    short* vT    = krb + 524288;               //   524,288 shorts
    short* wthi  = qb;                         // aliases qb (dead before rope_conv)
    short* wtlo  = wthi + 1638400;

    hipLaunchKernelGGL(xconv_kernel, dim3(2048), dim3(256), 0, stream, x, xhi, xlo);
    hipLaunchKernelGGL(wconv_kernel, dim3(50, 32), dim3(256), 0, stream,
                       Wq, Wk, Wv, Wg, wthi, wtlo);
    hipLaunchKernelGGL(proj_mfma_kernel, dim3(25, 16), dim3(512), 0, stream,
                       xhi, xlo, wthi, wtlo, q, k_raw, v, gsig);
    hipLaunchKernelGGL(rope_conv_kernel, dim3(512, 10), dim3(256), 0, stream,
                       q, k_raw, qb, krb);
    hipLaunchKernelGGL(vtrans_kernel, dim3(64, 4, 2), dim3(256), 0, stream,
                       v, vT);
    hipLaunchKernelGGL(pool_kernel, dim3(64), dim3(256), 0, stream,
                       k_raw, v, wk_pool, wv_pool, pe, k_cmp, v_cmp);
    hipLaunchKernelGGL(cmp_sel_kernel, dim3(2048, 2), dim3(64), 0, stream,
                       q, k_cmp, v_cmp, o_cmp, sel);
    hipLaunchKernelGGL(slcswa_kernel, dim3(128, 2), dim3(512), 0, stream,
                       qb, krb, vT, sel, gsig, o_cmp, out);
}

// Round 8
// 239.094 us; speedup vs baseline: 1.0085x; 1.0085x over previous
//
#include <hip/hip_runtime.h>
#include <math.h>

#define NEGF  (-1e30f)
#define BIGF  (1000000.0f)
#define SCALE_ (0.08838834764831845f)   // 1/sqrt(128)
#define L2INV_ (0.20762050593046014f)   // log2(10000)/64

typedef __attribute__((ext_vector_type(4))) float f32x4;
typedef __attribute__((ext_vector_type(8))) short short8;
typedef __attribute__((ext_vector_type(4))) short short4v;
typedef __attribute__((ext_vector_type(8))) _Float16 half8;

#define GLDS16(gp, lp) __builtin_amdgcn_global_load_lds( \
    (const __attribute__((address_space(1))) void*)(gp), \
    (__attribute__((address_space(3))) void*)(lp), 16, 0, 0)

__device__ __forceinline__ float wave_max(float v) {
    #pragma unroll
    for (int off = 32; off >= 1; off >>= 1) v = fmaxf(v, __shfl_xor(v, off, 64));
    return v;
}
__device__ __forceinline__ float wave_sum(float v) {
    #pragma unroll
    for (int off = 32; off >= 1; off >>= 1) v += __shfl_xor(v, off, 64);
    return v;
}
__device__ __forceinline__ short bf16_of(float f) {
    union { float f; unsigned u; } x; x.f = f;
    unsigned r = x.u + 0x7fffu + ((x.u >> 16) & 1u);
    return (short)(r >> 16);
}
__device__ __forceinline__ short f16_of(float f) {
    _Float16 h = (_Float16)f;
    union { _Float16 h; short s; } u; u.h = h;
    return u.s;
}
__device__ __forceinline__ float f32_of_f16(short s) {
    union { _Float16 h; short s; } u; u.s = s;
    return (float)u.h;
}

// -------- Kernel 0a: x (fp32) -> xhi/xlo fp16 split ------------------------
__global__ __launch_bounds__(256) void xconv_kernel(
    const float* __restrict__ x, short* __restrict__ xhi, short* __restrict__ xlo)
{
    const int i = blockIdx.x * 1024 + threadIdx.x * 4;
    float4 f = *(const float4*)(x + i);
    short4v hi, lo;
    float fv[4] = {f.x, f.y, f.z, f.w};
    #pragma unroll
    for (int c = 0; c < 4; ++c) {
        short h = f16_of(fv[c]);
        hi[c] = h;
        lo[c] = f16_of(fv[c] - f32_of_f16(h));
    }
    *(short4v*)(xhi + i) = hi;
    *(short4v*)(xlo + i) = lo;
}

// -------- Kernel 0b: W's -> WT fp16 split, transposed [1600][1024] ---------
__global__ __launch_bounds__(256) void wconv_kernel(
    const float* __restrict__ Wq, const float* __restrict__ Wk,
    const float* __restrict__ Wv, const float* __restrict__ Wg,
    short* __restrict__ wthi, short* __restrict__ wtlo)
{
    __shared__ float tile[32][33];
    const int ct = blockIdx.x, kt = blockIdx.y;
    const int c = threadIdx.x & 31, r0 = threadIdx.x >> 5;
    #pragma unroll
    for (int rr = 0; rr < 32; rr += 8) {
        int k = kt * 32 + r0 + rr;
        int gc = ct * 32 + c;
        float val;
        if (gc < 1024)      val = Wq[k * 1024 + gc];
        else if (gc < 1280) val = Wk[k * 256 + gc - 1024];
        else if (gc < 1536) val = Wv[k * 256 + gc - 1280];
        else if (gc < 1560) val = Wg[k * 24 + gc - 1536];
        else                val = 0.f;
        tile[r0 + rr][c] = val;
    }
    __syncthreads();
    #pragma unroll
    for (int rr = 0; rr < 32; rr += 8) {
        int col = ct * 32 + r0 + rr;
        int k = kt * 32 + c;
        float val = tile[c][r0 + rr];
        short hi = f16_of(val);
        short lo = f16_of(val - f32_of_f16(hi));
        wthi[(size_t)col * 1024 + k] = hi;
        wtlo[(size_t)col * 1024 + k] = lo;
    }
}

// -------- Kernel 1: projections via split-fp16 MFMA, LDS-staged ------------
__global__ __launch_bounds__(512, 2) void proj_mfma_kernel(
    const short* __restrict__ xhi, const short* __restrict__ xlo,
    const short* __restrict__ wthi, const short* __restrict__ wtlo,
    float* __restrict__ q, float* __restrict__ k_raw,
    float* __restrict__ v, float* __restrict__ gsig)
{
    __shared__ __align__(16) short lds[24576];
    const int cb = blockIdx.x;
    const int tb = blockIdx.y;
    const int w = threadIdx.x >> 6;
    const int l = threadIdx.x & 63;
    const int l16 = l & 15, g4 = l >> 4;
    const int wm = w >> 1, wn = w & 1;
    const int row0 = tb * 128, col0 = cb * 64;

    const short* pAhi[2]; const short* pAlo[2];
    #pragma unroll
    for (int j = 0; j < 2; ++j) {
        int b = (2 * w + j) * 1024 + l * 16;
        int row = b >> 7;
        int kb = (b & 127) ^ ((row & 7) << 4);
        pAhi[j] = xhi + (size_t)(row0 + row) * 1024 + (kb >> 1);
        pAlo[j] = xlo + (size_t)(row0 + row) * 1024 + (kb >> 1);
    }
    const short* pBhi; const short* pBlo;
    {
        int b = w * 1024 + l * 16;
        int col = b >> 7;
        int kb = (b & 127) ^ ((col & 7) << 4);
        pBhi = wthi + (size_t)(col0 + col) * 1024 + (kb >> 1);
        pBlo = wtlo + (size_t)(col0 + col) * 1024 + (kb >> 1);
    }

    f32x4 acc[2][2];
    #pragma unroll
    for (int mt = 0; mt < 2; ++mt)
        #pragma unroll
        for (int nt = 0; nt < 2; ++nt) acc[mt][nt] = (f32x4)0.f;

    for (int k0 = 0; k0 < 1024; k0 += 64) {
        GLDS16(pAhi[0] + k0, &lds[(2 * w + 0) * 512]);
        GLDS16(pAhi[1] + k0, &lds[(2 * w + 1) * 512]);
        GLDS16(pAlo[0] + k0, &lds[8192 + (2 * w + 0) * 512]);
        GLDS16(pAlo[1] + k0, &lds[8192 + (2 * w + 1) * 512]);
        GLDS16(pBhi + k0,    &lds[16384 + w * 512]);
        GLDS16(pBlo + k0,    &lds[20480 + w * 512]);
        __syncthreads();
        #pragma unroll
        for (int ksub = 0; ksub < 2; ++ksub) {
            half8 ah[2], al[2], bh[2], bl[2];
            #pragma unroll
            for (int mt = 0; mt < 2; ++mt) {
                int row = wm * 32 + mt * 16 + l16;
                int kb = (ksub * 64 + g4 * 16) ^ ((row & 7) << 4);
                ah[mt] = *(const half8*)(const void*)&lds[row * 64 + (kb >> 1)];
                al[mt] = *(const half8*)(const void*)&lds[8192 + row * 64 + (kb >> 1)];
            }
            #pragma unroll
            for (int nt = 0; nt < 2; ++nt) {
                int col = wn * 32 + nt * 16 + l16;
                int kb = (ksub * 64 + g4 * 16) ^ ((col & 7) << 4);
                bh[nt] = *(const half8*)(const void*)&lds[16384 + col * 64 + (kb >> 1)];
                bl[nt] = *(const half8*)(const void*)&lds[20480 + col * 64 + (kb >> 1)];
            }
            #pragma unroll
            for (int mt = 0; mt < 2; ++mt)
                #pragma unroll
                for (int nt = 0; nt < 2; ++nt) {
                    acc[mt][nt] = __builtin_amdgcn_mfma_f32_16x16x32_f16(ah[mt], bh[nt], acc[mt][nt], 0, 0, 0);
                    acc[mt][nt] = __builtin_amdgcn_mfma_f32_16x16x32_f16(ah[mt], bl[nt], acc[mt][nt], 0, 0, 0);
                    acc[mt][nt] = __builtin_amdgcn_mfma_f32_16x16x32_f16(al[mt], bh[nt], acc[mt][nt], 0, 0, 0);
                }
        }
        __syncthreads();
    }
    #pragma unroll
    for (int mt = 0; mt < 2; ++mt) {
        #pragma unroll
        for (int r = 0; r < 4; ++r) {
            const int tt = row0 + wm * 32 + mt * 16 + g4 * 4 + r;
            #pragma unroll
            for (int nt = 0; nt < 2; ++nt) {
                const int cg = col0 + wn * 32 + nt * 16 + l16;
                const float val = acc[mt][nt][r];
                if (cg < 1024)      q[(size_t)tt * 1024 + cg] = val;
                else if (cg < 1280) k_raw[(size_t)tt * 256 + cg - 1024] = val;
                else if (cg < 1536) v[(size_t)tt * 256 + cg - 1280] = val;
                else if (cg < 1560) gsig[(size_t)tt * 24 + cg - 1536] = 1.0f / (1.0f + expf(-val));
            }
        }
    }
}

// ------ Kernel 2: RoPE on q (in place) and k, plus bf16 copies -------------
__global__ __launch_bounds__(256) void rope_conv_kernel(
    float* __restrict__ q, const float* __restrict__ k_raw,
    short* __restrict__ qb, short* __restrict__ krb)
{
    const int t = blockIdx.x * 4 + (threadIdx.x >> 6);
    const int h = blockIdx.y;
    const int i = threadIdx.x & 63;
    float inv = exp2f(-(float)i * L2INV_);
    float ang = (float)t * inv;
    float sn, cs;
    sincosf(ang, &sn, &cs);
    if (h < 8) {
        float* p = q + t * 1024 + h * 128;
        float x1 = p[i], x2 = p[i + 64];
        float r1 = x1 * cs - x2 * sn;
        float r2 = x1 * sn + x2 * cs;
        p[i] = r1; p[i + 64] = r2;
        qb[t * 1024 + h * 128 + i]      = bf16_of(r1);
        qb[t * 1024 + h * 128 + i + 64] = bf16_of(r2);
    } else {
        const float* s = k_raw + t * 256 + (h - 8) * 128;
        float x1 = s[i], x2 = s[i + 64];
        krb[t * 256 + (h - 8) * 128 + i]      = bf16_of(x1 * cs - x2 * sn);
        krb[t * 256 + (h - 8) * 128 + i + 64] = bf16_of(x1 * sn + x2 * cs);
    }
}

// ------ Kernel 2b: v (fp32 [s][kv][d]) -> vT bf16 [kv][d][s] ---------------
__global__ __launch_bounds__(256) void vtrans_kernel(
    const float* __restrict__ v, short* __restrict__ vT)
{
    __shared__ short tile[32][33];
    const int s0 = blockIdx.x * 32, d0 = blockIdx.y * 32, kv = blockIdx.z;
    const int c = threadIdx.x & 31, r0 = threadIdx.x >> 5;
    #pragma unroll
    for (int rr = 0; rr < 32; rr += 8) {
        int r = r0 + rr;
        tile[r][c] = bf16_of(v[((size_t)(s0 + r) * 2 + kv) * 128 + d0 + c]);
    }
    __syncthreads();
    #pragma unroll
    for (int rr = 0; rr < 32; rr += 8) {
        int r = r0 + rr;
        vT[((size_t)kv * 128 + d0 + r) * 2048 + s0 + c] = tile[c][r];
    }
}

// ------- Kernel 3: pooled k_cmp (roped at j*32) and v_cmp ------------------
__global__ __launch_bounds__(256) void pool_kernel(
    const float* __restrict__ k_raw, const float* __restrict__ v_raw,
    const float* __restrict__ wk_pool, const float* __restrict__ wv_pool,
    const float* __restrict__ pe, float* __restrict__ k_cmp, float* __restrict__ v_cmp)
{
    const int j = blockIdx.x;
    const int tid = threadIdx.x;
    const int kv = tid >> 7, d = tid & 127;
    float ak = 0.f, av = 0.f;
    for (int s = 0; s < 32; ++s) {
        float pev = pe[(kv * 32 + s) * 128 + d];
        float kk = k_raw[((j * 32 + s) * 2 + kv) * 128 + d] + pev;
        float vv = v_raw[((j * 32 + s) * 2 + kv) * 128 + d] + pev;
        ak += kk * wk_pool[kv * 32 + s];
        av += vv * wv_pool[kv * 32 + s];
    }
    __shared__ float sk[256];
    sk[tid] = ak;
    __syncthreads();
    int i = d & 63;
    float inv = exp2f(-(float)i * L2INV_);
    float ang = (float)(j * 32) * inv;
    float sn, cs; sincosf(ang, &sn, &cs);
    float x1 = sk[kv * 128 + i], x2 = sk[kv * 128 + i + 64];
    float outv = (d < 64) ? (x1 * cs - x2 * sn) : (x1 * sn + x2 * cs);
    k_cmp[(j * 2 + kv) * 128 + d] = outv;
    v_cmp[(j * 2 + kv) * 128 + d] = av;
}

// ------- Kernel 4: compressed attention + pw + top-8 selection (fp32) ------
__global__ __launch_bounds__(64) void cmp_sel_kernel(
    const float* __restrict__ q, const float* __restrict__ k_cmp,
    const float* __restrict__ v_cmp, float* __restrict__ o_cmp,
    unsigned long long* __restrict__ sel_mask)
{
    const int t = blockIdx.x;
    const int kv = blockIdx.y;
    const int lane = threadIdx.x;
    __shared__ float qs[4][128];
    __shared__ float ps[64];
    for (int idx = lane; idx < 512; idx += 64)
        qs[idx >> 7][idx & 127] = q[t * 1024 + kv * 512 + idx];
    __syncthreads();
    const int j = lane;
    const float4* krow = (const float4*)&k_cmp[(j * 2 + kv) * 128];
    const bool vis = (t >= j * 32 + 31);
    const bool anyvis = (t >= 31);
    float pw = 0.f;
    for (int g = 0; g < 4; ++g) {
        const float4* qrow = (const float4*)qs[g];
        float s = 0.f;
        #pragma unroll 8
        for (int ii = 0; ii < 32; ++ii) {
            float4 kk = krow[ii], qq = qrow[ii];
            s += kk.x * qq.x + kk.y * qq.y + kk.z * qq.z + kk.w * qq.w;
        }
        s *= SCALE_;
        s = vis ? s : NEGF;
        float m = wave_max(s);
        float e = expf(s - m);
        float sum = wave_sum(e);
        float p = anyvis ? (e / sum) : 0.f;
        pw += p;
        ps[lane] = p;
        __syncthreads();
        float o0 = 0.f, o1 = 0.f;
        for (int jj = 0; jj < 64; ++jj) {
            float pp = ps[jj];
            o0 += pp * v_cmp[(jj * 2 + kv) * 128 + lane];
            o1 += pp * v_cmp[(jj * 2 + kv) * 128 + lane + 64];
        }
        o_cmp[t * 1024 + kv * 512 + g * 128 + lane]      = o0;
        o_cmp[t * 1024 + kv * 512 + g * 128 + lane + 64] = o1;
        __syncthreads();
    }
    const int cur = t >> 5;
    const int curm1 = cur > 0 ? cur - 1 : 0;
    const bool forced = (j == 0) || (j == cur) || (j == curm1);
    const bool allowed = (j * 32 <= t);
    float sc = allowed ? (pw + (forced ? BIGF : 0.f)) : -1.0f;
    unsigned long long selm = 0ull;
    for (int it = 0; it < 8; ++it) {
        float bv = sc; int bi = j;
        #pragma unroll
        for (int off = 32; off >= 1; off >>= 1) {
            float ov = __shfl_xor(bv, off, 64);
            int   oi = __shfl_xor(bi, off, 64);
            if (ov > bv || (ov == bv && oi < bi)) { bv = ov; bi = oi; }
        }
        if (bv > -0.5f) selm |= (1ull << bi);
        if (j == bi) sc = -3e38f;
    }
    if (lane == 0) sel_mask[t * 2 + kv] = selm;
}

// ------- Kernel 5: fused slc+swa, wave-pair split, spill-free regalloc -----
// block = (16-query tile, kv), 8 waves. Pair (w, w+4) shares g=w&3:
// half = w>>2. Phase 1: slc blocks bi%2==half; merge. Phase 2: swa chunks
// ci%2==half; merge. Swapped-operand QK^T (per-lane softmax) throughout.
__global__ __launch_bounds__(512, 2) void slcswa_kernel(
    const short* __restrict__ qb, const short* __restrict__ krb,
    const short* __restrict__ vT, const unsigned long long* __restrict__ sel,
    const float* __restrict__ gsig, const float* __restrict__ o_cmp,
    float* __restrict__ out)
{
    const int t0 = blockIdx.x * 16;
    const int kv = blockIdx.y;
    const int w  = threadIdx.x >> 6;       // 0..7
    const int l  = threadIdx.x & 63;
    const int l16 = l & 15, g4 = l >> 4;
    const int g  = w & 3;
    const int half = w >> 2;               // 0 = merger (A), 1 = partial (B)
    __shared__ __align__(16) short plds[8][16][40];
    __shared__ float o_slc[4][16][132];
    __shared__ float o_swa[4][16][132];
    __shared__ float mBp[4][16], lBp[4][16];
    __shared__ float gl[16][12];
    __shared__ unsigned long long qm[16];
    __shared__ unsigned char blist[64];
    __shared__ int nbs;
    if (threadIdx.x < 16) qm[threadIdx.x] = sel[(size_t)(t0 + threadIdx.x) * 2 + kv];
    if (threadIdx.x >= 64 && threadIdx.x < 256) {
        int idx = threadIdx.x - 64;
        gl[idx / 12][idx % 12] = gsig[(size_t)(t0 + idx / 12) * 24 + kv * 12 + idx % 12];
    }
    __syncthreads();
    if (threadIdx.x == 0) {
        unsigned long long u = 0ull;
        #pragma unroll
        for (int i = 0; i < 16; ++i) u |= qm[i];
        int n = 0;
        while (u) { blist[n++] = (unsigned char)(__ffsll((long long)u) - 1); u &= u - 1; }
        nbs = n;
    }
    __syncthreads();

    // Q fragment (B-operand: cols = queries)
    short8 qf[4];
    #pragma unroll
    for (int ks = 0; ks < 4; ++ks)
        qf[ks] = *(const short8*)(qb + ((size_t)(t0 + l16) * 8 + kv * 4 + g) * 128 + ks * 32 + g4 * 8);
    const int tq = t0 + l16;

    // ================= phase 1: selected =================
    {
        f32x4 acc[8];
        #pragma unroll
        for (int dt = 0; dt < 8; ++dt) acc[dt] = (f32x4)0.f;
        float m_r = NEGF, l_r = 0.f;
        const unsigned long long myqm = qm[l16];
        const int nb = nbs;
        for (int bi = half; bi < nb; bi += 2) {
            const int j = blist[bi];
            const int s0 = j * 32;
            f32x4 sct[2];
            sct[0] = (f32x4)0.f; sct[1] = (f32x4)0.f;
            #pragma unroll
            for (int nt = 0; nt < 2; ++nt) {
                short8 kf[4];
                #pragma unroll
                for (int ks = 0; ks < 4; ++ks)
                    kf[ks] = *(const short8*)(krb + ((size_t)(s0 + nt * 16 + l16) * 2 + kv) * 128 + ks * 32 + g4 * 8);
                #pragma unroll
                for (int ks = 0; ks < 4; ++ks)
                    sct[nt] = __builtin_amdgcn_mfma_f32_16x16x32_bf16(kf[ks], qf[ks], sct[nt], 0, 0, 0);
            }
            const bool inm = (myqm >> j) & 1ull;
            float p[8];
            float mx = NEGF;
            #pragma unroll
            for (int nt = 0; nt < 2; ++nt)
                #pragma unroll
                for (int r = 0; r < 4; ++r) {
                    const int key = s0 + nt * 16 + g4 * 4 + r;
                    const bool vv = inm && (key <= tq);
                    const float sv = vv ? sct[nt][r] * SCALE_ : NEGF;
                    p[nt * 4 + r] = sv;
                    mx = fmaxf(mx, sv);
                }
            mx = fmaxf(mx, __shfl_xor(mx, 16, 64));
            mx = fmaxf(mx, __shfl_xor(mx, 32, 64));
            const float mnew = fmaxf(m_r, mx);
            const float alx = __expf(m_r - mnew);
            float rs = 0.f;
            #pragma unroll
            for (int i = 0; i < 8; ++i) { float pv = __expf(p[i] - mnew); p[i] = pv; rs += pv; }
            rs += __shfl_xor(rs, 16, 64);
            rs += __shfl_xor(rs, 32, 64);
            l_r = l_r * alx + rs;
            m_r = mnew;
            #pragma unroll
            for (int dt = 0; dt < 8; ++dt) acc[dt] *= alx;
            #pragma unroll
            for (int nt = 0; nt < 2; ++nt)
                #pragma unroll
                for (int r = 0; r < 4; ++r)
                    plds[w][l16][nt * 16 + g4 * 4 + r] = bf16_of(p[nt * 4 + r]);
            short8 pa = *(const short8*)(&plds[w][l16][g4 * 8]);
            #pragma unroll
            for (int dt = 0; dt < 8; ++dt) {
                short8 vf = *(const short8*)(vT + ((size_t)kv * 128 + dt * 16 + l16) * 2048 + s0 + g4 * 8);
                acc[dt] = __builtin_amdgcn_mfma_f32_16x16x32_bf16(vf, pa, acc[dt], 0, 0, 0);
            }
        }
        if (half == 1) {
            if (g4 == 0) { mBp[g][l16] = m_r; lBp[g][l16] = l_r; }
            #pragma unroll
            for (int dt = 0; dt < 8; ++dt)
                #pragma unroll
                for (int r = 0; r < 4; ++r)
                    o_slc[g][l16][dt * 16 + g4 * 4 + r] = acc[dt][r];
        }
        __syncthreads();
        if (half == 0) {
            const float mBv = mBp[g][l16], lBv = lBp[g][l16];
            const float mm = fmaxf(m_r, mBv);
            const float aA = __expf(m_r - mm);
            const float aB = __expf(mBv - mm);
            const float rl = 1.0f / (l_r * aA + lBv * aB);
            #pragma unroll
            for (int dt = 0; dt < 8; ++dt)
                #pragma unroll
                for (int r = 0; r < 4; ++r) {
                    const int idx = dt * 16 + g4 * 4 + r;
                    o_slc[g][l16][idx] = (acc[dt][r] * aA + o_slc[g][l16][idx] * aB) * rl;
                }
        }
    }
    __syncthreads();
    // ================= phase 2: sliding window =================
    {
        f32x4 acc[8];
        #pragma unroll
        for (int dt = 0; dt < 8; ++dt) acc[dt] = (f32x4)0.f;
        float m_r = NEGF, l_r = 0.f;
        const int sLo = (t0 >= 256) ? (t0 - 256) : 0;
        for (int s0 = sLo + half * 32; s0 <= t0 + 15; s0 += 64) {
            f32x4 sct[2];
            sct[0] = (f32x4)0.f; sct[1] = (f32x4)0.f;
            #pragma unroll
            for (int nt = 0; nt < 2; ++nt) {
                short8 kf[4];
                int sr = s0 + nt * 16 + l16;
                if (sr > 2047) sr = 2047;          // clamp; masked below
                #pragma unroll
                for (int ks = 0; ks < 4; ++ks)
                    kf[ks] = *(const short8*)(krb + ((size_t)sr * 2 + kv) * 128 + ks * 32 + g4 * 8);
                #pragma unroll
                for (int ks = 0; ks < 4; ++ks)
                    sct[nt] = __builtin_amdgcn_mfma_f32_16x16x32_bf16(kf[ks], qf[ks], sct[nt], 0, 0, 0);
            }
            float p[8];
            float mx = NEGF;
            #pragma unroll
            for (int nt = 0; nt < 2; ++nt)
                #pragma unroll
                for (int r = 0; r < 4; ++r) {
                    const int key = s0 + nt * 16 + g4 * 4 + r;
                    const bool vv = (key <= tq) && (key >= tq - 256);
                    const float sv = vv ? sct[nt][r] * SCALE_ : NEGF;
                    p[nt * 4 + r] = sv;
                    mx = fmaxf(mx, sv);
                }
            mx = fmaxf(mx, __shfl_xor(mx, 16, 64));
            mx = fmaxf(mx, __shfl_xor(mx, 32, 64));
            const float mnew = fmaxf(m_r, mx);
            const float alx = __expf(m_r - mnew);
            float rs = 0.f;
            #pragma unroll
            for (int i = 0; i < 8; ++i) { float pv = __expf(p[i] - mnew); p[i] = pv; rs += pv; }
            rs += __shfl_xor(rs, 16, 64);
            rs += __shfl_xor(rs, 32, 64);
            l_r = l_r * alx + rs;
            m_r = mnew;
            #pragma unroll
            for (int dt = 0; dt < 8; ++dt) acc[dt] *= alx;
            #pragma unroll
            for (int nt = 0; nt < 2; ++nt)
                #pragma unroll
                for (int r = 0; r < 4; ++r)
                    plds[w][l16][nt * 16 + g4 * 4 + r] = bf16_of(p[nt * 4 + r]);
            short8 pa = *(const short8*)(&plds[w][l16][g4 * 8]);
            int sc0 = s0 + g4 * 8;
            if (sc0 > 2040) sc0 = 2040;            // clamp; those p's are 0
            #pragma unroll
            for (int dt = 0; dt < 8; ++dt) {
                short8 vf = *(const short8*)(vT + ((size_t)kv * 128 + dt * 16 + l16) * 2048 + sc0);
                acc[dt] = __builtin_amdgcn_mfma_f32_16x16x32_bf16(vf, pa, acc[dt], 0, 0, 0);
            }
        }
        if (half == 1) {
            if (g4 == 0) { mBp[g][l16] = m_r; lBp[g][l16] = l_r; }
            #pragma unroll
            for (int dt = 0; dt < 8; ++dt)
                #pragma unroll
                for (int r = 0; r < 4; ++r)
                    o_swa[g][l16][dt * 16 + g4 * 4 + r] = acc[dt][r];
        }
        __syncthreads();
        if (half == 0) {
            const float mBv = mBp[g][l16], lBv = lBp[g][l16];
            const float mm = fmaxf(m_r, mBv);
            const float aA = __expf(m_r - mm);
            const float aB = __expf(mBv - mm);
            const float rl = 1.0f / (l_r * aA + lBv * aB);
            #pragma unroll
            for (int dt = 0; dt < 8; ++dt)
                #pragma unroll
                for (int r = 0; r < 4; ++r) {
                    const int idx = dt * 16 + g4 * 4 + r;
                    o_swa[g][l16][idx] = (acc[dt][r] * aA + o_swa[g][l16][idx] * aB) * rl;
                }
        }
    }
    __syncthreads();
    // ---------------- gated combine (coalesced, all 512 threads) -----------
    for (int idx = threadIdx.x; idx < 8192; idx += 512) {
        const int qq = idx >> 9, c = idx & 511;
        const int gg = c >> 7, d = c & 127;
        const size_t oidx = (size_t)(t0 + qq) * 1024 + kv * 512 + c;
        out[oidx] = gl[qq][gg * 3 + 0] * o_cmp[oidx]
                  + gl[qq][gg * 3 + 1] * o_slc[gg][qq][d]
                  + gl[qq][gg * 3 + 2] * o_swa[gg][qq][d];
    }
}

extern "C" void kernel_launch(void* const* d_in, const int* in_sizes, int n_in,
                              void* d_out, int out_size, void* d_ws, size_t ws_size,
                              hipStream_t stream)
{
    const float* x       = (const float*)d_in[0];
    const float* Wq      = (const float*)d_in[1];
    const float* Wk      = (const float*)d_in[2];
    const float* Wv      = (const float*)d_in[3];
    const float* Wg      = (const float*)d_in[4];
    const float* wk_pool = (const float*)d_in[5];
    const float* wv_pool = (const float*)d_in[6];
    const float* pe      = (const float*)d_in[7];
    float* out = (float*)d_out;
    float* ws  = (float*)d_ws;

    float* q     = ws;                         // 2,097,152
    float* k_raw = q + 2097152;                //   524,288
    float* v     = k_raw + 524288;             //   524,288
    float* gsig  = v + 524288;                 //    49,152
    float* k_cmp = gsig + 49152;               //    16,384
    float* v_cmp = k_cmp + 16384;              //    16,384
    unsigned long long* sel = (unsigned long long*)(v_cmp + 16384); // 8,192 f
    float* o_cmp = (float*)sel + 8192;         // 2,097,152
    short* xhi   = (short*)o_cmp;              // aliases o_cmp (dead before cmp_sel)
    short* xlo   = xhi + 2097152;
    short* qb    = (short*)(o_cmp + 2097152);  // 2,097,152 shorts
    short* krb   = qb + 2097152;               //   524,288 shorts
    short* vT    = krb + 524288;               //   524,288 shorts
    short* wthi  = qb;                         // aliases qb (dead before rope_conv)
    short* wtlo  = wthi + 1638400;

    hipLaunchKernelGGL(xconv_kernel, dim3(2048), dim3(256), 0, stream, x, xhi, xlo);
    hipLaunchKernelGGL(wconv_kernel, dim3(50, 32), dim3(256), 0, stream,
                       Wq, Wk, Wv, Wg, wthi, wtlo);
    hipLaunchKernelGGL(proj_mfma_kernel, dim3(25, 16), dim3(512), 0, stream,
                       xhi, xlo, wthi, wtlo, q, k_raw, v, gsig);
    hipLaunchKernelGGL(rope_conv_kernel, dim3(512, 10), dim3(256), 0, stream,
                       q, k_raw, qb, krb);
    hipLaunchKernelGGL(vtrans_kernel, dim3(64, 4, 2), dim3(256), 0, stream,
                       v, vT);
    hipLaunchKernelGGL(pool_kernel, dim3(64), dim3(256), 0, stream,
                       k_raw, v, wk_pool, wv_pool, pe, k_cmp, v_cmp);
    hipLaunchKernelGGL(cmp_sel_kernel, dim3(2048, 2), dim3(64), 0, stream,
                       q, k_cmp, v_cmp, o_cmp, sel);
    hipLaunchKernelGGL(slcswa_kernel, dim3(128, 2), dim3(512), 0, stream,
                       qb, krb, vT, sel, gsig, o_cmp, out);
}

// Round 9
// 196.074 us; speedup vs baseline: 1.2298x; 1.2194x over previous
//
#include <hip/hip_runtime.h>
#include <math.h>

#define NEGF  (-1e30f)
#define BIGF  (1000000.0f)
#define SCALE_ (0.08838834764831845f)   // 1/sqrt(128)
#define L2INV_ (0.20762050593046014f)   // log2(10000)/64
#define QT 4

typedef __attribute__((ext_vector_type(4))) float f32x4;
typedef __attribute__((ext_vector_type(8))) short short8;
typedef __attribute__((ext_vector_type(4))) short short4v;
typedef __attribute__((ext_vector_type(8))) _Float16 half8;

#define GLDS16(gp, lp) __builtin_amdgcn_global_load_lds( \
    (const __attribute__((address_space(1))) void*)(gp), \
    (__attribute__((address_space(3))) void*)(lp), 16, 0, 0)

__device__ __forceinline__ float wave_max(float v) {
    #pragma unroll
    for (int off = 32; off >= 1; off >>= 1) v = fmaxf(v, __shfl_xor(v, off, 64));
    return v;
}
__device__ __forceinline__ float wave_sum(float v) {
    #pragma unroll
    for (int off = 32; off >= 1; off >>= 1) v += __shfl_xor(v, off, 64);
    return v;
}
__device__ __forceinline__ short bf16_of(float f) {
    union { float f; unsigned u; } x; x.f = f;
    unsigned r = x.u + 0x7fffu + ((x.u >> 16) & 1u);
    return (short)(r >> 16);
}
__device__ __forceinline__ float f32_of_bf16bits(unsigned u16) {
    union { unsigned u; float f; } x; x.u = u16 << 16;
    return x.f;
}
__device__ __forceinline__ short f16_of(float f) {
    _Float16 h = (_Float16)f;
    union { _Float16 h; short s; } u; u.h = h;
    return u.s;
}
__device__ __forceinline__ float f32_of_f16(short s) {
    union { _Float16 h; short s; } u; u.s = s;
    return (float)u.h;
}

// -------- Kernel 0a: x (fp32) -> xhi/xlo fp16 split ------------------------
__global__ __launch_bounds__(256) void xconv_kernel(
    const float* __restrict__ x, short* __restrict__ xhi, short* __restrict__ xlo)
{
    const int i = blockIdx.x * 1024 + threadIdx.x * 4;
    float4 f = *(const float4*)(x + i);
    short4v hi, lo;
    float fv[4] = {f.x, f.y, f.z, f.w};
    #pragma unroll
    for (int c = 0; c < 4; ++c) {
        short h = f16_of(fv[c]);
        hi[c] = h;
        lo[c] = f16_of(fv[c] - f32_of_f16(h));
    }
    *(short4v*)(xhi + i) = hi;
    *(short4v*)(xlo + i) = lo;
}

// -------- Kernel 0b: W's -> WT fp16 split, transposed [1600][1024] ---------
__global__ __launch_bounds__(256) void wconv_kernel(
    const float* __restrict__ Wq, const float* __restrict__ Wk,
    const float* __restrict__ Wv, const float* __restrict__ Wg,
    short* __restrict__ wthi, short* __restrict__ wtlo)
{
    __shared__ float tile[32][33];
    const int ct = blockIdx.x, kt = blockIdx.y;
    const int c = threadIdx.x & 31, r0 = threadIdx.x >> 5;
    #pragma unroll
    for (int rr = 0; rr < 32; rr += 8) {
        int k = kt * 32 + r0 + rr;
        int gc = ct * 32 + c;
        float val;
        if (gc < 1024)      val = Wq[k * 1024 + gc];
        else if (gc < 1280) val = Wk[k * 256 + gc - 1024];
        else if (gc < 1536) val = Wv[k * 256 + gc - 1280];
        else if (gc < 1560) val = Wg[k * 24 + gc - 1536];
        else                val = 0.f;
        tile[r0 + rr][c] = val;
    }
    __syncthreads();
    #pragma unroll
    for (int rr = 0; rr < 32; rr += 8) {
        int col = ct * 32 + r0 + rr;
        int k = kt * 32 + c;
        float val = tile[c][r0 + rr];
        short hi = f16_of(val);
        short lo = f16_of(val - f32_of_f16(hi));
        wthi[(size_t)col * 1024 + k] = hi;
        wtlo[(size_t)col * 1024 + k] = lo;
    }
}

// -------- Kernel 1: projections via split-fp16 MFMA, LDS-staged ------------
__global__ __launch_bounds__(512, 2) void proj_mfma_kernel(
    const short* __restrict__ xhi, const short* __restrict__ xlo,
    const short* __restrict__ wthi, const short* __restrict__ wtlo,
    float* __restrict__ q, float* __restrict__ k_raw,
    float* __restrict__ v, float* __restrict__ gsig)
{
    __shared__ __align__(16) short lds[24576];
    const int cb = blockIdx.x;
    const int tb = blockIdx.y;
    const int w = threadIdx.x >> 6;
    const int l = threadIdx.x & 63;
    const int l16 = l & 15, g4 = l >> 4;
    const int wm = w >> 1, wn = w & 1;
    const int row0 = tb * 128, col0 = cb * 64;

    const short* pAhi[2]; const short* pAlo[2];
    #pragma unroll
    for (int j = 0; j < 2; ++j) {
        int b = (2 * w + j) * 1024 + l * 16;
        int row = b >> 7;
        int kb = (b & 127) ^ ((row & 7) << 4);
        pAhi[j] = xhi + (size_t)(row0 + row) * 1024 + (kb >> 1);
        pAlo[j] = xlo + (size_t)(row0 + row) * 1024 + (kb >> 1);
    }
    const short* pBhi; const short* pBlo;
    {
        int b = w * 1024 + l * 16;
        int col = b >> 7;
        int kb = (b & 127) ^ ((col & 7) << 4);
        pBhi = wthi + (size_t)(col0 + col) * 1024 + (kb >> 1);
        pBlo = wtlo + (size_t)(col0 + col) * 1024 + (kb >> 1);
    }

    f32x4 acc[2][2];
    #pragma unroll
    for (int mt = 0; mt < 2; ++mt)
        #pragma unroll
        for (int nt = 0; nt < 2; ++nt) acc[mt][nt] = (f32x4)0.f;

    for (int k0 = 0; k0 < 1024; k0 += 64) {
        GLDS16(pAhi[0] + k0, &lds[(2 * w + 0) * 512]);
        GLDS16(pAhi[1] + k0, &lds[(2 * w + 1) * 512]);
        GLDS16(pAlo[0] + k0, &lds[8192 + (2 * w + 0) * 512]);
        GLDS16(pAlo[1] + k0, &lds[8192 + (2 * w + 1) * 512]);
        GLDS16(pBhi + k0,    &lds[16384 + w * 512]);
        GLDS16(pBlo + k0,    &lds[20480 + w * 512]);
        __syncthreads();
        #pragma unroll
        for (int ksub = 0; ksub < 2; ++ksub) {
            half8 ah[2], al[2], bh[2], bl[2];
            #pragma unroll
            for (int mt = 0; mt < 2; ++mt) {
                int row = wm * 32 + mt * 16 + l16;
                int kb = (ksub * 64 + g4 * 16) ^ ((row & 7) << 4);
                ah[mt] = *(const half8*)(const void*)&lds[row * 64 + (kb >> 1)];
                al[mt] = *(const half8*)(const void*)&lds[8192 + row * 64 + (kb >> 1)];
            }
            #pragma unroll
            for (int nt = 0; nt < 2; ++nt) {
                int col = wn * 32 + nt * 16 + l16;
                int kb = (ksub * 64 + g4 * 16) ^ ((col & 7) << 4);
                bh[nt] = *(const half8*)(const void*)&lds[16384 + col * 64 + (kb >> 1)];
                bl[nt] = *(const half8*)(const void*)&lds[20480 + col * 64 + (kb >> 1)];
            }
            #pragma unroll
            for (int mt = 0; mt < 2; ++mt)
                #pragma unroll
                for (int nt = 0; nt < 2; ++nt) {
                    acc[mt][nt] = __builtin_amdgcn_mfma_f32_16x16x32_f16(ah[mt], bh[nt], acc[mt][nt], 0, 0, 0);
                    acc[mt][nt] = __builtin_amdgcn_mfma_f32_16x16x32_f16(ah[mt], bl[nt], acc[mt][nt], 0, 0, 0);
                    acc[mt][nt] = __builtin_amdgcn_mfma_f32_16x16x32_f16(al[mt], bh[nt], acc[mt][nt], 0, 0, 0);
                }
        }
        __syncthreads();
    }
    #pragma unroll
    for (int mt = 0; mt < 2; ++mt) {
        #pragma unroll
        for (int r = 0; r < 4; ++r) {
            const int tt = row0 + wm * 32 + mt * 16 + g4 * 4 + r;
            #pragma unroll
            for (int nt = 0; nt < 2; ++nt) {
                const int cg = col0 + wn * 32 + nt * 16 + l16;
                const float val = acc[mt][nt][r];
                if (cg < 1024)      q[(size_t)tt * 1024 + cg] = val;
                else if (cg < 1280) k_raw[(size_t)tt * 256 + cg - 1024] = val;
                else if (cg < 1536) v[(size_t)tt * 256 + cg - 1280] = val;
                else if (cg < 1560) gsig[(size_t)tt * 24 + cg - 1536] = 1.0f / (1.0f + expf(-val));
            }
        }
    }
}

// ------ Kernel 2: RoPE on q (in place) and k, plus bf16 copies -------------
__global__ __launch_bounds__(256) void rope_conv_kernel(
    float* __restrict__ q, const float* __restrict__ k_raw,
    short* __restrict__ qb, short* __restrict__ krb)
{
    const int t = blockIdx.x * 4 + (threadIdx.x >> 6);
    const int h = blockIdx.y;
    const int i = threadIdx.x & 63;
    float inv = exp2f(-(float)i * L2INV_);
    float ang = (float)t * inv;
    float sn, cs;
    sincosf(ang, &sn, &cs);
    if (h < 8) {
        float* p = q + t * 1024 + h * 128;
        float x1 = p[i], x2 = p[i + 64];
        float r1 = x1 * cs - x2 * sn;
        float r2 = x1 * sn + x2 * cs;
        p[i] = r1; p[i + 64] = r2;
        qb[t * 1024 + h * 128 + i]      = bf16_of(r1);
        qb[t * 1024 + h * 128 + i + 64] = bf16_of(r2);
    } else {
        const float* s = k_raw + t * 256 + (h - 8) * 128;
        float x1 = s[i], x2 = s[i + 64];
        krb[t * 256 + (h - 8) * 128 + i]      = bf16_of(x1 * cs - x2 * sn);
        krb[t * 256 + (h - 8) * 128 + i + 64] = bf16_of(x1 * sn + x2 * cs);
    }
}

// ------ Kernel 2b: v (fp32 [s][kv][d]) -> vT bf16 [kv][d][s] ---------------
__global__ __launch_bounds__(256) void vtrans_kernel(
    const float* __restrict__ v, short* __restrict__ vT)
{
    __shared__ short tile[32][33];
    const int s0 = blockIdx.x * 32, d0 = blockIdx.y * 32, kv = blockIdx.z;
    const int c = threadIdx.x & 31, r0 = threadIdx.x >> 5;
    #pragma unroll
    for (int rr = 0; rr < 32; rr += 8) {
        int r = r0 + rr;
        tile[r][c] = bf16_of(v[((size_t)(s0 + r) * 2 + kv) * 128 + d0 + c]);
    }
    __syncthreads();
    #pragma unroll
    for (int rr = 0; rr < 32; rr += 8) {
        int r = r0 + rr;
        vT[((size_t)kv * 128 + d0 + r) * 2048 + s0 + c] = tile[c][r];
    }
}

// ------- Kernel 3: pooled k_cmp (roped at j*32) and v_cmp ------------------
__global__ __launch_bounds__(256) void pool_kernel(
    const float* __restrict__ k_raw, const float* __restrict__ v_raw,
    const float* __restrict__ wk_pool, const float* __restrict__ wv_pool,
    const float* __restrict__ pe, float* __restrict__ k_cmp, float* __restrict__ v_cmp)
{
    const int j = blockIdx.x;
    const int tid = threadIdx.x;
    const int kv = tid >> 7, d = tid & 127;
    float ak = 0.f, av = 0.f;
    for (int s = 0; s < 32; ++s) {
        float pev = pe[(kv * 32 + s) * 128 + d];
        float kk = k_raw[((j * 32 + s) * 2 + kv) * 128 + d] + pev;
        float vv = v_raw[((j * 32 + s) * 2 + kv) * 128 + d] + pev;
        ak += kk * wk_pool[kv * 32 + s];
        av += vv * wv_pool[kv * 32 + s];
    }
    __shared__ float sk[256];
    sk[tid] = ak;
    __syncthreads();
    int i = d & 63;
    float inv = exp2f(-(float)i * L2INV_);
    float ang = (float)(j * 32) * inv;
    float sn, cs; sincosf(ang, &sn, &cs);
    float x1 = sk[kv * 128 + i], x2 = sk[kv * 128 + i + 64];
    float outv = (d < 64) ? (x1 * cs - x2 * sn) : (x1 * sn + x2 * cs);
    k_cmp[(j * 2 + kv) * 128 + d] = outv;
    v_cmp[(j * 2 + kv) * 128 + d] = av;
}

// ------- Kernel 4: compressed attention + pw + top-8 selection (fp32) ------
__global__ __launch_bounds__(64) void cmp_sel_kernel(
    const float* __restrict__ q, const float* __restrict__ k_cmp,
    const float* __restrict__ v_cmp, float* __restrict__ o_cmp,
    unsigned long long* __restrict__ sel_mask)
{
    const int t = blockIdx.x;
    const int kv = blockIdx.y;
    const int lane = threadIdx.x;
    __shared__ float qs[4][128];
    __shared__ float ps[64];
    for (int idx = lane; idx < 512; idx += 64)
        qs[idx >> 7][idx & 127] = q[t * 1024 + kv * 512 + idx];
    __syncthreads();
    const int j = lane;
    const float4* krow = (const float4*)&k_cmp[(j * 2 + kv) * 128];
    const bool vis = (t >= j * 32 + 31);
    const bool anyvis = (t >= 31);
    float pw = 0.f;
    for (int g = 0; g < 4; ++g) {
        const float4* qrow = (const float4*)qs[g];
        float s = 0.f;
        #pragma unroll 8
        for (int ii = 0; ii < 32; ++ii) {
            float4 kk = krow[ii], qq = qrow[ii];
            s += kk.x * qq.x + kk.y * qq.y + kk.z * qq.z + kk.w * qq.w;
        }
        s *= SCALE_;
        s = vis ? s : NEGF;
        float m = wave_max(s);
        float e = expf(s - m);
        float sum = wave_sum(e);
        float p = anyvis ? (e / sum) : 0.f;
        pw += p;
        ps[lane] = p;
        __syncthreads();
        float o0 = 0.f, o1 = 0.f;
        for (int jj = 0; jj < 64; ++jj) {
            float pp = ps[jj];
            o0 += pp * v_cmp[(jj * 2 + kv) * 128 + lane];
            o1 += pp * v_cmp[(jj * 2 + kv) * 128 + lane + 64];
        }
        o_cmp[t * 1024 + kv * 512 + g * 128 + lane]      = o0;
        o_cmp[t * 1024 + kv * 512 + g * 128 + lane + 64] = o1;
        __syncthreads();
    }
    const int cur = t >> 5;
    const int curm1 = cur > 0 ? cur - 1 : 0;
    const bool forced = (j == 0) || (j == cur) || (j == curm1);
    const bool allowed = (j * 32 <= t);
    float sc = allowed ? (pw + (forced ? BIGF : 0.f)) : -1.0f;
    unsigned long long selm = 0ull;
    for (int it = 0; it < 8; ++it) {
        float bv = sc; int bi = j;
        #pragma unroll
        for (int off = 32; off >= 1; off >>= 1) {
            float ov = __shfl_xor(bv, off, 64);
            int   oi = __shfl_xor(bi, off, 64);
            if (ov > bv || (ov == bv && oi < bi)) { bv = ov; bi = oi; }
        }
        if (bv > -0.5f) selm |= (1ull << bi);
        if (j == bi) sc = -3e38f;
    }
    if (lane == 0) sel_mask[t * 2 + kv] = selm;
}

// ------- Kernel 5: fused slc+swa, 4-q tiles, LDS-staged K/V dbuf -----------
// block = (4-query tile, kv), 4 waves (wave = g). grid (512,2) = 1024 blocks
// -> 4 blocks/CU, 16 waves/CU. Unified entry list (slc items then swa
// chunks); K/V tiles double-buffered in LDS via global_load_lds with
// both-sides XOR swizzle; one acc set reused (o_slc parked as packed bf16).
__global__ __launch_bounds__(256, 4) void slcswa_kernel(
    const short* __restrict__ qb, const short* __restrict__ krb,
    const short* __restrict__ vT, const unsigned long long* __restrict__ sel,
    const float* __restrict__ gsig, const float* __restrict__ o_cmp,
    float* __restrict__ out)
{
    const int t0 = blockIdx.x * QT;
    const int kv = blockIdx.y;
    const int w  = threadIdx.x >> 6;       // 0..3 = g
    const int l  = threadIdx.x & 63;
    const int l16 = l & 15, g4 = l >> 4;
    const int g  = w;
    __shared__ __align__(16) short kbuf[2][4096];   // 8KB per buf
    __shared__ __align__(16) short vbuf[2][4096];   // 8KB per buf
    __shared__ __align__(16) short plds[4][16][40];
    __shared__ int list_s0[48];
    __shared__ unsigned char list_md[48];
    __shared__ unsigned long long qm[QT];
    __shared__ int ne_s, nslc_s;

    if (threadIdx.x < QT) qm[threadIdx.x] = sel[(size_t)(t0 + threadIdx.x) * 2 + kv];
    __syncthreads();
    if (threadIdx.x == 0) {
        unsigned long long u = 0ull;
        #pragma unroll
        for (int i = 0; i < QT; ++i) u |= qm[i];
        int n = 0;
        while (u) { int j = __ffsll((long long)u) - 1; list_s0[n] = j * 32; list_md[n] = 0; ++n; u &= u - 1; }
        nslc_s = n;
        int sLo = (t0 >= 256) ? ((t0 - 256) & ~31) : 0;
        for (int s0 = sLo; s0 <= t0 + QT - 1; s0 += 32) { list_s0[n] = s0; list_md[n] = 1; ++n; }
        ne_s = n;
    }
    __syncthreads();
    const int ne = ne_s, nslc = nslc_s;

    // Q fragment (B-operand cols = queries; lanes l16>=QT duplicate query l16&3)
    const int tq = t0 + (l16 & (QT - 1));
    const unsigned long long myqm = qm[l16 & (QT - 1)];
    short8 qf[4];
    #pragma unroll
    for (int ks = 0; ks < 4; ++ks)
        qf[ks] = *(const short8*)(qb + ((size_t)tq * 8 + kv * 4 + g) * 128 + ks * 32 + g4 * 8);

    // ---- staging: K tile (32 keys x 256B) + V tile (128 d x 64B), swizzled
    #define STAGE_KV(buf, s0v)                                                    \
    {                                                                             \
        _Pragma("unroll")                                                         \
        for (int sw = 0; sw < 2; ++sw) {                                          \
            int off = sw * 4096 + w * 1024 + (l << 4);                            \
            int row = off >> 8, col = off & 255;                                  \
            int cs = col ^ ((row & 7) << 4);                                      \
            const short* src = krb + (((size_t)((s0v) + row) * 2 + kv) << 7) + (cs >> 1); \
            GLDS16(src, &kbuf[buf][(sw * 4096 + w * 1024) >> 1]);                 \
        }                                                                         \
        _Pragma("unroll")                                                         \
        for (int sw = 0; sw < 2; ++sw) {                                          \
            int off = sw * 4096 + w * 1024 + (l << 4);                            \
            int row = off >> 6, col = off & 63;                                   \
            int cs = col ^ ((row & 3) << 4);                                      \
            const short* src = vT + (size_t)(kv * 128 + row) * 2048 + (s0v) + (cs >> 1); \
            GLDS16(src, &vbuf[buf][(sw * 4096 + w * 1024) >> 1]);                 \
        }                                                                         \
    }

    f32x4 acc[8];
    #pragma unroll
    for (int dt = 0; dt < 8; ++dt) acc[dt] = (f32x4)0.f;
    float m_r = NEGF, l_r = 0.f;
    unsigned oslc_pk[16];

    STAGE_KV(0, list_s0[0]);
    __syncthreads();

    for (int e = 0; e < ne; ++e) {
        const int s0 = list_s0[e];
        const int md = list_md[e];
        const int cur = e & 1;
        if (e + 1 < ne) STAGE_KV(cur ^ 1, list_s0[e + 1]);

        // QK^T (swapped): S^T[key][query]
        f32x4 sct[2];
        sct[0] = (f32x4)0.f; sct[1] = (f32x4)0.f;
        #pragma unroll
        for (int nt = 0; nt < 2; ++nt) {
            const int row = nt * 16 + l16;
            short8 kf[4];
            #pragma unroll
            for (int ks = 0; ks < 4; ++ks)
                kf[ks] = *(const short8*)&kbuf[cur][(row * 256 + ((ks * 64 + g4 * 16) ^ ((row & 7) << 4))) >> 1];
            #pragma unroll
            for (int ks = 0; ks < 4; ++ks)
                sct[nt] = __builtin_amdgcn_mfma_f32_16x16x32_bf16(kf[ks], qf[ks], sct[nt], 0, 0, 0);
        }
        // mask + per-lane softmax
        const bool inm = md ? true : ((myqm >> (s0 >> 5)) & 1ull);
        float p[8];
        float mx = NEGF;
        #pragma unroll
        for (int nt = 0; nt < 2; ++nt)
            #pragma unroll
            for (int r = 0; r < 4; ++r) {
                const int key = s0 + nt * 16 + g4 * 4 + r;
                const bool vv = md ? ((key <= tq) && (key >= tq - 256))
                                   : (inm && (key <= tq));
                const float sv = vv ? sct[nt][r] * SCALE_ : NEGF;
                p[nt * 4 + r] = sv;
                mx = fmaxf(mx, sv);
            }
        mx = fmaxf(mx, __shfl_xor(mx, 16, 64));
        mx = fmaxf(mx, __shfl_xor(mx, 32, 64));
        const float mnew = fmaxf(m_r, mx);
        const float alx = __expf(m_r - mnew);
        float rs = 0.f;
        #pragma unroll
        for (int i = 0; i < 8; ++i) { float pv = __expf(p[i] - mnew); p[i] = pv; rs += pv; }
        rs += __shfl_xor(rs, 16, 64);
        rs += __shfl_xor(rs, 32, 64);
        l_r = l_r * alx + rs;
        m_r = mnew;
        #pragma unroll
        for (int dt = 0; dt < 8; ++dt) acc[dt] *= alx;
        // P -> LDS -> B-frag
        short4v pk0, pk1;
        #pragma unroll
        for (int r = 0; r < 4; ++r) { pk0[r] = bf16_of(p[r]); pk1[r] = bf16_of(p[4 + r]); }
        *(short4v*)&plds[w][l16][g4 * 4]      = pk0;
        *(short4v*)&plds[w][l16][16 + g4 * 4] = pk1;
        short8 pa = *(const short8*)(&plds[w][l16][g4 * 8]);
        // PV from staged V tile
        #pragma unroll
        for (int dt = 0; dt < 8; ++dt) {
            const int row = dt * 16 + l16;
            short8 vf = *(const short8*)&vbuf[cur][(row * 64 + ((g4 * 16) ^ ((row & 3) << 4))) >> 1];
            acc[dt] = __builtin_amdgcn_mfma_f32_16x16x32_bf16(vf, pa, acc[dt], 0, 0, 0);
        }
        // phase boundary: park normalized o_slc as packed bf16, reset state
        if (e == nslc - 1) {
            const float rl = 1.0f / l_r;
            #pragma unroll
            for (int dt = 0; dt < 8; ++dt) {
                oslc_pk[dt * 2 + 0] = ((unsigned)(unsigned short)bf16_of(acc[dt][0]))
                                    | (((unsigned)(unsigned short)bf16_of(acc[dt][1] * rl)) << 16);
                // note: pack both with rl applied
                oslc_pk[dt * 2 + 0] = ((unsigned)(unsigned short)bf16_of(acc[dt][0] * rl))
                                    | (((unsigned)(unsigned short)bf16_of(acc[dt][1] * rl)) << 16);
                oslc_pk[dt * 2 + 1] = ((unsigned)(unsigned short)bf16_of(acc[dt][2] * rl))
                                    | (((unsigned)(unsigned short)bf16_of(acc[dt][3] * rl)) << 16);
                acc[dt] = (f32x4)0.f;
            }
            m_r = NEGF; l_r = 0.f;
        }
        __syncthreads();   // staging e+1 drained (implicit waitcnt) + all waves done with buf[cur]
    }

    // ---- combine + store (lanes with l16 < QT only) ----
    if (l16 < QT) {
        const float rlw = 1.0f / l_r;
        const float gc = gsig[(size_t)tq * 24 + kv * 12 + g * 3 + 0];
        const float gs = gsig[(size_t)tq * 24 + kv * 12 + g * 3 + 1];
        const float gw = gsig[(size_t)tq * 24 + kv * 12 + g * 3 + 2];
        #pragma unroll
        for (int dt = 0; dt < 8; ++dt)
            #pragma unroll
            for (int r = 0; r < 4; ++r) {
                const int d = dt * 16 + g4 * 4 + r;
                const unsigned pk = oslc_pk[dt * 2 + (r >> 1)];
                const float osl = f32_of_bf16bits((r & 1) ? (pk >> 16) : (pk & 0xffffu));
                const size_t idx = (size_t)tq * 1024 + (kv * 4 + g) * 128 + d;
                out[idx] = gc * o_cmp[idx] + gs * osl + gw * acc[dt][r] * rlw;
            }
    }
}

extern "C" void kernel_launch(void* const* d_in, const int* in_sizes, int n_in,
                              void* d_out, int out_size, void* d_ws, size_t ws_size,
                              hipStream_t stream)
{
    const float* x       = (const float*)d_in[0];
    const float* Wq      = (const float*)d_in[1];
    const float* Wk      = (const float*)d_in[2];
    const float* Wv      = (const float*)d_in[3];
    const float* Wg      = (const float*)d_in[4];
    const float* wk_pool = (const float*)d_in[5];
    const float* wv_pool = (const float*)d_in[6];
    const float* pe      = (const float*)d_in[7];
    float* out = (float*)d_out;
    float* ws  = (float*)d_ws;

    float* q     = ws;                         // 2,097,152
    float* k_raw = q + 2097152;                //   524,288
    float* v     = k_raw + 524288;             //   524,288
    float* gsig  = v + 524288;                 //    49,152
    float* k_cmp = gsig + 49152;               //    16,384
    float* v_cmp = k_cmp + 16384;              //    16,384
    unsigned long long* sel = (unsigned long long*)(v_cmp + 16384); // 8,192 f
    float* o_cmp = (float*)sel + 8192;         // 2,097,152
    short* xhi   = (short*)o_cmp;              // aliases o_cmp (dead before cmp_sel)
    short* xlo   = xhi + 2097152;
    short* qb    = (short*)(o_cmp + 2097152);  // 2,097,152 shorts
    short* krb   = qb + 2097152;               //   524,288 shorts
    short* vT    = krb + 524288;               //   524,288 shorts
    short* wthi  = qb;                         // aliases qb (dead before rope_conv)
    short* wtlo  = wthi + 1638400;

    hipLaunchKernelGGL(xconv_kernel, dim3(2048), dim3(256), 0, stream, x, xhi, xlo);
    hipLaunchKernelGGL(wconv_kernel, dim3(50, 32), dim3(256), 0, stream,
                       Wq, Wk, Wv, Wg, wthi, wtlo);
    hipLaunchKernelGGL(proj_mfma_kernel, dim3(25, 16), dim3(512), 0, stream,
                       xhi, xlo, wthi, wtlo, q, k_raw, v, gsig);
    hipLaunchKernelGGL(rope_conv_kernel, dim3(512, 10), dim3(256), 0, stream,
                       q, k_raw, qb, krb);
    hipLaunchKernelGGL(vtrans_kernel, dim3(64, 4, 2), dim3(256), 0, stream,
                       v, vT);
    hipLaunchKernelGGL(pool_kernel, dim3(64), dim3(256), 0, stream,
                       k_raw, v, wk_pool, wv_pool, pe, k_cmp, v_cmp);
    hipLaunchKernelGGL(cmp_sel_kernel, dim3(2048, 2), dim3(64), 0, stream,
                       q, k_cmp, v_cmp, o_cmp, sel);
    hipLaunchKernelGGL(slcswa_kernel, dim3(512, 2), dim3(256), 0, stream,
                       qb, krb, vT, sel, gsig, o_cmp, out);
}

// Round 10
// 150.149 us; speedup vs baseline: 1.6059x; 1.3059x over previous
//
#include <hip/hip_runtime.h>
#include <math.h>

#define NEGF  (-1e30f)
#define BIGF  (1000000.0f)
#define SCALE_ (0.08838834764831845f)   // 1/sqrt(128)
#define L2INV_ (0.20762050593046014f)   // log2(10000)/64
#define QT 4

typedef __attribute__((ext_vector_type(4))) float f32x4;
typedef __attribute__((ext_vector_type(8))) short short8;
typedef __attribute__((ext_vector_type(4))) short short4v;
typedef __attribute__((ext_vector_type(8))) _Float16 half8;

#define GLDS16(gp, lp) __builtin_amdgcn_global_load_lds( \
    (const __attribute__((address_space(1))) void*)(gp), \
    (__attribute__((address_space(3))) void*)(lp), 16, 0, 0)

__device__ __forceinline__ short bf16_of(float f) {
    union { float f; unsigned u; } x; x.f = f;
    unsigned r = x.u + 0x7fffu + ((x.u >> 16) & 1u);
    return (short)(r >> 16);
}
__device__ __forceinline__ float f32_of_bf16bits(unsigned u16) {
    union { unsigned u; float f; } x; x.u = u16 << 16;
    return x.f;
}
__device__ __forceinline__ short f16_of(float f) {
    _Float16 h = (_Float16)f;
    union { _Float16 h; short s; } u; u.h = h;
    return u.s;
}
__device__ __forceinline__ float f32_of_f16(short s) {
    union { _Float16 h; short s; } u; u.s = s;
    return (float)u.h;
}

// -------- Kernel 0a: x (fp32) -> xhi/xlo fp16 split ------------------------
__global__ __launch_bounds__(256) void xconv_kernel(
    const float* __restrict__ x, short* __restrict__ xhi, short* __restrict__ xlo)
{
    const int i = blockIdx.x * 1024 + threadIdx.x * 4;
    float4 f = *(const float4*)(x + i);
    short4v hi, lo;
    float fv[4] = {f.x, f.y, f.z, f.w};
    #pragma unroll
    for (int c = 0; c < 4; ++c) {
        short h = f16_of(fv[c]);
        hi[c] = h;
        lo[c] = f16_of(fv[c] - f32_of_f16(h));
    }
    *(short4v*)(xhi + i) = hi;
    *(short4v*)(xlo + i) = lo;
}

// -------- Kernel 0b: W's -> WT fp16 split, transposed [1600][1024] ---------
__global__ __launch_bounds__(256) void wconv_kernel(
    const float* __restrict__ Wq, const float* __restrict__ Wk,
    const float* __restrict__ Wv, const float* __restrict__ Wg,
    short* __restrict__ wthi, short* __restrict__ wtlo)
{
    __shared__ float tile[32][33];
    const int ct = blockIdx.x, kt = blockIdx.y;
    const int c = threadIdx.x & 31, r0 = threadIdx.x >> 5;
    #pragma unroll
    for (int rr = 0; rr < 32; rr += 8) {
        int k = kt * 32 + r0 + rr;
        int gc = ct * 32 + c;
        float val;
        if (gc < 1024)      val = Wq[k * 1024 + gc];
        else if (gc < 1280) val = Wk[k * 256 + gc - 1024];
        else if (gc < 1536) val = Wv[k * 256 + gc - 1280];
        else if (gc < 1560) val = Wg[k * 24 + gc - 1536];
        else                val = 0.f;
        tile[r0 + rr][c] = val;
    }
    __syncthreads();
    #pragma unroll
    for (int rr = 0; rr < 32; rr += 8) {
        int col = ct * 32 + r0 + rr;
        int k = kt * 32 + c;
        float val = tile[c][r0 + rr];
        short hi = f16_of(val);
        short lo = f16_of(val - f32_of_f16(hi));
        wthi[(size_t)col * 1024 + k] = hi;
        wtlo[(size_t)col * 1024 + k] = lo;
    }
}

// -------- Kernel 1: projections via split-fp16 MFMA, LDS-staged ------------
__global__ __launch_bounds__(512, 2) void proj_mfma_kernel(
    const short* __restrict__ xhi, const short* __restrict__ xlo,
    const short* __restrict__ wthi, const short* __restrict__ wtlo,
    float* __restrict__ q, float* __restrict__ k_raw,
    float* __restrict__ v, float* __restrict__ gsig)
{
    __shared__ __align__(16) short lds[24576];
    const int cb = blockIdx.x;
    const int tb = blockIdx.y;
    const int w = threadIdx.x >> 6;
    const int l = threadIdx.x & 63;
    const int l16 = l & 15, g4 = l >> 4;
    const int wm = w >> 1, wn = w & 1;
    const int row0 = tb * 128, col0 = cb * 64;

    const short* pAhi[2]; const short* pAlo[2];
    #pragma unroll
    for (int j = 0; j < 2; ++j) {
        int b = (2 * w + j) * 1024 + l * 16;
        int row = b >> 7;
        int kb = (b & 127) ^ ((row & 7) << 4);
        pAhi[j] = xhi + (size_t)(row0 + row) * 1024 + (kb >> 1);
        pAlo[j] = xlo + (size_t)(row0 + row) * 1024 + (kb >> 1);
    }
    const short* pBhi; const short* pBlo;
    {
        int b = w * 1024 + l * 16;
        int col = b >> 7;
        int kb = (b & 127) ^ ((col & 7) << 4);
        pBhi = wthi + (size_t)(col0 + col) * 1024 + (kb >> 1);
        pBlo = wtlo + (size_t)(col0 + col) * 1024 + (kb >> 1);
    }

    f32x4 acc[2][2];
    #pragma unroll
    for (int mt = 0; mt < 2; ++mt)
        #pragma unroll
        for (int nt = 0; nt < 2; ++nt) acc[mt][nt] = (f32x4)0.f;

    for (int k0 = 0; k0 < 1024; k0 += 64) {
        GLDS16(pAhi[0] + k0, &lds[(2 * w + 0) * 512]);
        GLDS16(pAhi[1] + k0, &lds[(2 * w + 1) * 512]);
        GLDS16(pAlo[0] + k0, &lds[8192 + (2 * w + 0) * 512]);
        GLDS16(pAlo[1] + k0, &lds[8192 + (2 * w + 1) * 512]);
        GLDS16(pBhi + k0,    &lds[16384 + w * 512]);
        GLDS16(pBlo + k0,    &lds[20480 + w * 512]);
        __syncthreads();
        #pragma unroll
        for (int ksub = 0; ksub < 2; ++ksub) {
            half8 ah[2], al[2], bh[2], bl[2];
            #pragma unroll
            for (int mt = 0; mt < 2; ++mt) {
                int row = wm * 32 + mt * 16 + l16;
                int kb = (ksub * 64 + g4 * 16) ^ ((row & 7) << 4);
                ah[mt] = *(const half8*)(const void*)&lds[row * 64 + (kb >> 1)];
                al[mt] = *(const half8*)(const void*)&lds[8192 + row * 64 + (kb >> 1)];
            }
            #pragma unroll
            for (int nt = 0; nt < 2; ++nt) {
                int col = wn * 32 + nt * 16 + l16;
                int kb = (ksub * 64 + g4 * 16) ^ ((col & 7) << 4);
                bh[nt] = *(const half8*)(const void*)&lds[16384 + col * 64 + (kb >> 1)];
                bl[nt] = *(const half8*)(const void*)&lds[20480 + col * 64 + (kb >> 1)];
            }
            #pragma unroll
            for (int mt = 0; mt < 2; ++mt)
                #pragma unroll
                for (int nt = 0; nt < 2; ++nt) {
                    acc[mt][nt] = __builtin_amdgcn_mfma_f32_16x16x32_f16(ah[mt], bh[nt], acc[mt][nt], 0, 0, 0);
                    acc[mt][nt] = __builtin_amdgcn_mfma_f32_16x16x32_f16(ah[mt], bl[nt], acc[mt][nt], 0, 0, 0);
                    acc[mt][nt] = __builtin_amdgcn_mfma_f32_16x16x32_f16(al[mt], bh[nt], acc[mt][nt], 0, 0, 0);
                }
        }
        __syncthreads();
    }
    #pragma unroll
    for (int mt = 0; mt < 2; ++mt) {
        #pragma unroll
        for (int r = 0; r < 4; ++r) {
            const int tt = row0 + wm * 32 + mt * 16 + g4 * 4 + r;
            #pragma unroll
            for (int nt = 0; nt < 2; ++nt) {
                const int cg = col0 + wn * 32 + nt * 16 + l16;
                const float val = acc[mt][nt][r];
                if (cg < 1024)      q[(size_t)tt * 1024 + cg] = val;
                else if (cg < 1280) k_raw[(size_t)tt * 256 + cg - 1024] = val;
                else if (cg < 1536) v[(size_t)tt * 256 + cg - 1280] = val;
                else if (cg < 1560) gsig[(size_t)tt * 24 + cg - 1536] = 1.0f / (1.0f + expf(-val));
            }
        }
    }
}

// ------ Kernel 2: RoPE on q (in place) + bf16 & fp16-split copies ----------
__global__ __launch_bounds__(256) void rope_conv_kernel(
    float* __restrict__ q, const float* __restrict__ k_raw,
    short* __restrict__ qb, short* __restrict__ krb,
    short* __restrict__ qhi, short* __restrict__ qlo)
{
    const int t = blockIdx.x * 4 + (threadIdx.x >> 6);
    const int h = blockIdx.y;
    const int i = threadIdx.x & 63;
    float inv = exp2f(-(float)i * L2INV_);
    float ang = (float)t * inv;
    float sn, cs;
    sincosf(ang, &sn, &cs);
    if (h < 8) {
        float* p = q + t * 1024 + h * 128;
        float x1 = p[i], x2 = p[i + 64];
        float r1 = x1 * cs - x2 * sn;
        float r2 = x1 * sn + x2 * cs;
        p[i] = r1; p[i + 64] = r2;
        const int o = t * 1024 + h * 128;
        qb[o + i]      = bf16_of(r1);
        qb[o + i + 64] = bf16_of(r2);
        short h1 = f16_of(r1), h2 = f16_of(r2);
        qhi[o + i] = h1;       qlo[o + i]      = f16_of(r1 - f32_of_f16(h1));
        qhi[o + i + 64] = h2;  qlo[o + i + 64] = f16_of(r2 - f32_of_f16(h2));
    } else {
        const float* s = k_raw + t * 256 + (h - 8) * 128;
        float x1 = s[i], x2 = s[i + 64];
        krb[t * 256 + (h - 8) * 128 + i]      = bf16_of(x1 * cs - x2 * sn);
        krb[t * 256 + (h - 8) * 128 + i + 64] = bf16_of(x1 * sn + x2 * cs);
    }
}

// ------ Kernel 2b: v (fp32 [s][kv][d]) -> vT bf16 [kv][d][s] ---------------
__global__ __launch_bounds__(256) void vtrans_kernel(
    const float* __restrict__ v, short* __restrict__ vT)
{
    __shared__ short tile[32][33];
    const int s0 = blockIdx.x * 32, d0 = blockIdx.y * 32, kv = blockIdx.z;
    const int c = threadIdx.x & 31, r0 = threadIdx.x >> 5;
    #pragma unroll
    for (int rr = 0; rr < 32; rr += 8) {
        int r = r0 + rr;
        tile[r][c] = bf16_of(v[((size_t)(s0 + r) * 2 + kv) * 128 + d0 + c]);
    }
    __syncthreads();
    #pragma unroll
    for (int rr = 0; rr < 32; rr += 8) {
        int r = r0 + rr;
        vT[((size_t)kv * 128 + d0 + r) * 2048 + s0 + c] = tile[c][r];
    }
}

// ------- Kernel 3: pool -> khi/klo (fp16 split, roped) + vcT (bf16 [kv][d][j])
__global__ __launch_bounds__(256) void pool_kernel(
    const float* __restrict__ k_raw, const float* __restrict__ v_raw,
    const float* __restrict__ wk_pool, const float* __restrict__ wv_pool,
    const float* __restrict__ pe, short* __restrict__ khi,
    short* __restrict__ klo, short* __restrict__ vcT)
{
    const int j = blockIdx.x;
    const int tid = threadIdx.x;
    const int kv = tid >> 7, d = tid & 127;
    float ak = 0.f, av = 0.f;
    for (int s = 0; s < 32; ++s) {
        float pev = pe[(kv * 32 + s) * 128 + d];
        float kk = k_raw[((j * 32 + s) * 2 + kv) * 128 + d] + pev;
        float vv = v_raw[((j * 32 + s) * 2 + kv) * 128 + d] + pev;
        ak += kk * wk_pool[kv * 32 + s];
        av += vv * wv_pool[kv * 32 + s];
    }
    __shared__ float sk[256];
    sk[tid] = ak;
    __syncthreads();
    int i = d & 63;
    float inv = exp2f(-(float)i * L2INV_);
    float ang = (float)(j * 32) * inv;
    float sn, cs; sincosf(ang, &sn, &cs);
    float x1 = sk[kv * 128 + i], x2 = sk[kv * 128 + i + 64];
    float outv = (d < 64) ? (x1 * cs - x2 * sn) : (x1 * sn + x2 * cs);
    short hi = f16_of(outv);
    khi[(j * 2 + kv) * 128 + d] = hi;
    klo[(j * 2 + kv) * 128 + d] = f16_of(outv - f32_of_f16(hi));
    vcT[((size_t)kv * 128 + d) * 64 + j] = bf16_of(av);
}

// ------- Kernel 4: compressed attention + pw + top-8, MFMA one-shot --------
// block = (16 queries, kv), 4 waves (wave = g). Swapped QK^T (lane = query),
// split-fp16 scores (fp32-class, selection-safe), bf16 PV, wave-argmax top-8.
__global__ __launch_bounds__(256) void cmp_mfma_kernel(
    const short* __restrict__ qhi, const short* __restrict__ qlo,
    const short* __restrict__ khi, const short* __restrict__ klo,
    const short* __restrict__ vcT, float* __restrict__ o_cmp,
    unsigned long long* __restrict__ sel_mask)
{
    const int t0 = blockIdx.x * 16;
    const int kv = blockIdx.y;
    const int g  = threadIdx.x >> 6;
    const int l  = threadIdx.x & 63;
    const int l16 = l & 15, g4 = l >> 4;
    __shared__ float pwpart[4][16][68];
    __shared__ __align__(16) short plds[4][16][72];
    const int tq = t0 + l16;

    half8 qfh[4], qfl[4];
    #pragma unroll
    for (int ks = 0; ks < 4; ++ks) {
        const size_t o = ((size_t)tq * 8 + kv * 4 + g) * 128 + ks * 32 + g4 * 8;
        qfh[ks] = *(const half8*)(const void*)(qhi + o);
        qfl[ks] = *(const half8*)(const void*)(qlo + o);
    }
    // scores S^T[j][query] over all 64 compressed blocks (4 tiles of 16)
    f32x4 sct[4];
    #pragma unroll
    for (int nt = 0; nt < 4; ++nt) {
        sct[nt] = (f32x4)0.f;
        #pragma unroll
        for (int ks = 0; ks < 4; ++ks) {
            const size_t o = ((size_t)(nt * 16 + l16) * 2 + kv) * 128 + ks * 32 + g4 * 8;
            half8 kfh = *(const half8*)(const void*)(khi + o);
            half8 kfl = *(const half8*)(const void*)(klo + o);
            sct[nt] = __builtin_amdgcn_mfma_f32_16x16x32_f16(kfh, qfh[ks], sct[nt], 0, 0, 0);
            sct[nt] = __builtin_amdgcn_mfma_f32_16x16x32_f16(kfh, qfl[ks], sct[nt], 0, 0, 0);
            sct[nt] = __builtin_amdgcn_mfma_f32_16x16x32_f16(kfl, qfh[ks], sct[nt], 0, 0, 0);
        }
    }
    // mask + one-shot softmax (per-lane = per-query)
    float p[16];
    float mx = NEGF;
    #pragma unroll
    for (int nt = 0; nt < 4; ++nt)
        #pragma unroll
        for (int r = 0; r < 4; ++r) {
            const int j = nt * 16 + g4 * 4 + r;
            const bool vis = (tq >= j * 32 + 31);
            const float sv = vis ? sct[nt][r] * SCALE_ : NEGF;
            p[nt * 4 + r] = sv;
            mx = fmaxf(mx, sv);
        }
    mx = fmaxf(mx, __shfl_xor(mx, 16, 64));
    mx = fmaxf(mx, __shfl_xor(mx, 32, 64));
    float rs = 0.f;
    #pragma unroll
    for (int i = 0; i < 16; ++i) {
        float pv = (p[i] > -1e29f) ? __expf(p[i] - mx) : 0.f;
        p[i] = pv;
        rs += pv;
    }
    rs += __shfl_xor(rs, 16, 64);
    rs += __shfl_xor(rs, 32, 64);
    const float rl = (rs > 0.f) ? 1.0f / rs : 0.f;
    // pw parts (normalized) + P bf16 to LDS
    #pragma unroll
    for (int nt = 0; nt < 4; ++nt)
        #pragma unroll
        for (int r = 0; r < 4; ++r) {
            const int j = nt * 16 + g4 * 4 + r;
            pwpart[g][l16][j] = p[nt * 4 + r] * rl;
            plds[g][l16][j]   = bf16_of(p[nt * 4 + r]);
        }
    // PV: O^T = v_cmp^T @ P^T  (2 K=32 steps over 64 keys)
    short8 pa0 = *(const short8*)(&plds[g][l16][g4 * 8]);
    short8 pa1 = *(const short8*)(&plds[g][l16][32 + g4 * 8]);
    f32x4 acc[8];
    #pragma unroll
    for (int dt = 0; dt < 8; ++dt) {
        const short* vr = vcT + ((size_t)kv * 128 + dt * 16 + l16) * 64;
        short8 vf0 = *(const short8*)(vr + g4 * 8);
        short8 vf1 = *(const short8*)(vr + 32 + g4 * 8);
        acc[dt] = (f32x4)0.f;
        acc[dt] = __builtin_amdgcn_mfma_f32_16x16x32_bf16(vf0, pa0, acc[dt], 0, 0, 0);
        acc[dt] = __builtin_amdgcn_mfma_f32_16x16x32_bf16(vf1, pa1, acc[dt], 0, 0, 0);
    }
    #pragma unroll
    for (int dt = 0; dt < 8; ++dt)
        #pragma unroll
        for (int r = 0; r < 4; ++r)
            o_cmp[(size_t)tq * 1024 + (kv * 4 + g) * 128 + dt * 16 + g4 * 4 + r] = acc[dt][r] * rl;
    __syncthreads();
    // top-8 selection: wave g handles queries g*4..g*4+3; lane = block j
    const int j = l;
    for (int qi = 0; qi < 4; ++qi) {
        const int qq = g * 4 + qi;
        const int tqq = t0 + qq;
        float pw = pwpart[0][qq][j] + pwpart[1][qq][j]
                 + pwpart[2][qq][j] + pwpart[3][qq][j];
        const int cur = tqq >> 5;
        const int curm1 = cur > 0 ? cur - 1 : 0;
        const bool forced = (j == 0) || (j == cur) || (j == curm1);
        const bool allowed = (j * 32 <= tqq);
        float sc = allowed ? (pw + (forced ? BIGF : 0.f)) : -1.0f;
        unsigned long long selm = 0ull;
        for (int it = 0; it < 8; ++it) {
            float bv = sc; int bi = j;
            #pragma unroll
            for (int off = 32; off >= 1; off >>= 1) {
                float ov = __shfl_xor(bv, off, 64);
                int   oi = __shfl_xor(bi, off, 64);
                if (ov > bv || (ov == bv && oi < bi)) { bv = ov; bi = oi; }
            }
            if (bv > -0.5f) selm |= (1ull << bi);
            if (j == bi) sc = -3e38f;
        }
        if (l == 0) sel_mask[(size_t)tqq * 2 + kv] = selm;
    }
}

// ------- Kernel 5: fused slc+swa, 4-q tiles, LDS-staged K/V dbuf -----------
__global__ __launch_bounds__(256, 4) void slcswa_kernel(
    const short* __restrict__ qb, const short* __restrict__ krb,
    const short* __restrict__ vT, const unsigned long long* __restrict__ sel,
    const float* __restrict__ gsig, const float* __restrict__ o_cmp,
    float* __restrict__ out)
{
    const int t0 = blockIdx.x * QT;
    const int kv = blockIdx.y;
    const int w  = threadIdx.x >> 6;       // 0..3 = g
    const int l  = threadIdx.x & 63;
    const int l16 = l & 15, g4 = l >> 4;
    const int g  = w;
    __shared__ __align__(16) short kbuf[2][4096];
    __shared__ __align__(16) short vbuf[2][4096];
    __shared__ __align__(16) short plds[4][16][40];
    __shared__ int list_s0[48];
    __shared__ unsigned char list_md[48];
    __shared__ unsigned long long qm[QT];
    __shared__ int ne_s, nslc_s;

    if (threadIdx.x < QT) qm[threadIdx.x] = sel[(size_t)(t0 + threadIdx.x) * 2 + kv];
    __syncthreads();
    if (threadIdx.x == 0) {
        unsigned long long u = 0ull;
        #pragma unroll
        for (int i = 0; i < QT; ++i) u |= qm[i];
        int n = 0;
        while (u) { int j = __ffsll((long long)u) - 1; list_s0[n] = j * 32; list_md[n] = 0; ++n; u &= u - 1; }
        nslc_s = n;
        int sLo = (t0 >= 256) ? ((t0 - 256) & ~31) : 0;
        for (int s0 = sLo; s0 <= t0 + QT - 1; s0 += 32) { list_s0[n] = s0; list_md[n] = 1; ++n; }
        ne_s = n;
    }
    __syncthreads();
    const int ne = ne_s, nslc = nslc_s;

    const int tq = t0 + (l16 & (QT - 1));
    const unsigned long long myqm = qm[l16 & (QT - 1)];
    short8 qf[4];
    #pragma unroll
    for (int ks = 0; ks < 4; ++ks)
        qf[ks] = *(const short8*)(qb + ((size_t)tq * 8 + kv * 4 + g) * 128 + ks * 32 + g4 * 8);

    #define STAGE_KV(buf, s0v)                                                    \
    {                                                                             \
        _Pragma("unroll")                                                         \
        for (int sw = 0; sw < 2; ++sw) {                                          \
            int off = sw * 4096 + w * 1024 + (l << 4);                            \
            int row = off >> 8, col = off & 255;                                  \
            int cs = col ^ ((row & 7) << 4);                                      \
            const short* src = krb + (((size_t)((s0v) + row) * 2 + kv) << 7) + (cs >> 1); \
            GLDS16(src, &kbuf[buf][(sw * 4096 + w * 1024) >> 1]);                 \
        }                                                                         \
        _Pragma("unroll")                                                         \
        for (int sw = 0; sw < 2; ++sw) {                                          \
            int off = sw * 4096 + w * 1024 + (l << 4);                            \
            int row = off >> 6, col = off & 63;                                   \
            int cs = col ^ ((row & 3) << 4);                                      \
            const short* src = vT + (size_t)(kv * 128 + row) * 2048 + (s0v) + (cs >> 1); \
            GLDS16(src, &vbuf[buf][(sw * 4096 + w * 1024) >> 1]);                 \
        }                                                                         \
    }

    f32x4 acc[8];
    #pragma unroll
    for (int dt = 0; dt < 8; ++dt) acc[dt] = (f32x4)0.f;
    float m_r = NEGF, l_r = 0.f;
    unsigned oslc_pk[16];

    STAGE_KV(0, list_s0[0]);
    __syncthreads();

    for (int e = 0; e < ne; ++e) {
        const int s0 = list_s0[e];
        const int md = list_md[e];
        const int cur = e & 1;
        if (e + 1 < ne) STAGE_KV(cur ^ 1, list_s0[e + 1]);

        f32x4 sct[2];
        sct[0] = (f32x4)0.f; sct[1] = (f32x4)0.f;
        #pragma unroll
        for (int nt = 0; nt < 2; ++nt) {
            const int row = nt * 16 + l16;
            short8 kf[4];
            #pragma unroll
            for (int ks = 0; ks < 4; ++ks)
                kf[ks] = *(const short8*)&kbuf[cur][(row * 256 + ((ks * 64 + g4 * 16) ^ ((row & 7) << 4))) >> 1];
            #pragma unroll
            for (int ks = 0; ks < 4; ++ks)
                sct[nt] = __builtin_amdgcn_mfma_f32_16x16x32_bf16(kf[ks], qf[ks], sct[nt], 0, 0, 0);
        }
        const bool inm = md ? true : ((myqm >> (s0 >> 5)) & 1ull);
        float p[8];
        float mx = NEGF;
        #pragma unroll
        for (int nt = 0; nt < 2; ++nt)
            #pragma unroll
            for (int r = 0; r < 4; ++r) {
                const int key = s0 + nt * 16 + g4 * 4 + r;
                const bool vv = md ? ((key <= tq) && (key >= tq - 256))
                                   : (inm && (key <= tq));
                const float sv = vv ? sct[nt][r] * SCALE_ : NEGF;
                p[nt * 4 + r] = sv;
                mx = fmaxf(mx, sv);
            }
        mx = fmaxf(mx, __shfl_xor(mx, 16, 64));
        mx = fmaxf(mx, __shfl_xor(mx, 32, 64));
        const float mnew = fmaxf(m_r, mx);
        const float alx = __expf(m_r - mnew);
        float rs = 0.f;
        #pragma unroll
        for (int i = 0; i < 8; ++i) { float pv = __expf(p[i] - mnew); p[i] = pv; rs += pv; }
        rs += __shfl_xor(rs, 16, 64);
        rs += __shfl_xor(rs, 32, 64);
        l_r = l_r * alx + rs;
        m_r = mnew;
        #pragma unroll
        for (int dt = 0; dt < 8; ++dt) acc[dt] *= alx;
        short4v pk0, pk1;
        #pragma unroll
        for (int r = 0; r < 4; ++r) { pk0[r] = bf16_of(p[r]); pk1[r] = bf16_of(p[4 + r]); }
        *(short4v*)&plds[w][l16][g4 * 4]      = pk0;
        *(short4v*)&plds[w][l16][16 + g4 * 4] = pk1;
        short8 pa = *(const short8*)(&plds[w][l16][g4 * 8]);
        #pragma unroll
        for (int dt = 0; dt < 8; ++dt) {
            const int row = dt * 16 + l16;
            short8 vf = *(const short8*)&vbuf[cur][(row * 64 + ((g4 * 16) ^ ((row & 3) << 4))) >> 1];
            acc[dt] = __builtin_amdgcn_mfma_f32_16x16x32_bf16(vf, pa, acc[dt], 0, 0, 0);
        }
        if (e == nslc - 1) {
            const float rl = 1.0f / l_r;
            #pragma unroll
            for (int dt = 0; dt < 8; ++dt) {
                oslc_pk[dt * 2 + 0] = ((unsigned)(unsigned short)bf16_of(acc[dt][0] * rl))
                                    | (((unsigned)(unsigned short)bf16_of(acc[dt][1] * rl)) << 16);
                oslc_pk[dt * 2 + 1] = ((unsigned)(unsigned short)bf16_of(acc[dt][2] * rl))
                                    | (((unsigned)(unsigned short)bf16_of(acc[dt][3] * rl)) << 16);
                acc[dt] = (f32x4)0.f;
            }
            m_r = NEGF; l_r = 0.f;
        }
        __syncthreads();
    }

    if (l16 < QT) {
        const float rlw = 1.0f / l_r;
        const float gc = gsig[(size_t)tq * 24 + kv * 12 + g * 3 + 0];
        const float gs = gsig[(size_t)tq * 24 + kv * 12 + g * 3 + 1];
        const float gw = gsig[(size_t)tq * 24 + kv * 12 + g * 3 + 2];
        #pragma unroll
        for (int dt = 0; dt < 8; ++dt)
            #pragma unroll
            for (int r = 0; r < 4; ++r) {
                const int d = dt * 16 + g4 * 4 + r;
                const unsigned pk = oslc_pk[dt * 2 + (r >> 1)];
                const float osl = f32_of_bf16bits((r & 1) ? (pk >> 16) : (pk & 0xffffu));
                const size_t idx = (size_t)tq * 1024 + (kv * 4 + g) * 128 + d;
                out[idx] = gc * o_cmp[idx] + gs * osl + gw * acc[dt][r] * rlw;
            }
    }
}

extern "C" void kernel_launch(void* const* d_in, const int* in_sizes, int n_in,
                              void* d_out, int out_size, void* d_ws, size_t ws_size,
                              hipStream_t stream)
{
    const float* x       = (const float*)d_in[0];
    const float* Wq      = (const float*)d_in[1];
    const float* Wk      = (const float*)d_in[2];
    const float* Wv      = (const float*)d_in[3];
    const float* Wg      = (const float*)d_in[4];
    const float* wk_pool = (const float*)d_in[5];
    const float* wv_pool = (const float*)d_in[6];
    const float* pe      = (const float*)d_in[7];
    float* out = (float*)d_out;
    float* ws  = (float*)d_ws;

    // ---- workspace layout (floats); total ~36.1 MB ----
    float* q     = ws;                         // 2,097,152
    float* k_raw = q + 2097152;                //   524,288
    float* v     = k_raw + 524288;             //   524,288
    float* gsig  = v + 524288;                 //    49,152
    unsigned long long* sel = (unsigned long long*)(gsig + 49152); // 8,192 f
    float* o_cmp = (float*)sel + 8192;         // 2,097,152
    short* xhi   = (short*)o_cmp;              // alias o_cmp (dead before cmp writes)
    short* xlo   = xhi + 2097152;
    short* qb    = (short*)(o_cmp + 2097152);  // 2,097,152 sh
    short* krb   = qb + 2097152;               //   524,288 sh
    short* vT    = krb + 524288;               //   524,288 sh
    short* khi   = vT + 524288;                //    16,384 sh  (in wtlo tail pad)
    short* klo   = khi + 16384;                //    16,384 sh
    short* vcT   = klo + 16384;                //    16,384 sh
    short* wthi  = qb;                         // alias qb.. (dead before rope/pool)
    short* wtlo  = wthi + 1638400;             // spans krb/vT/pad (131,072-sh pad)
    short* qhi   = qb + 3276800;               // 2,097,152 sh (after wtlo end)
    short* qlo   = qhi + 2097152;              // 2,097,152 sh

    hipLaunchKernelGGL(xconv_kernel, dim3(2048), dim3(256), 0, stream, x, xhi, xlo);
    hipLaunchKernelGGL(wconv_kernel, dim3(50, 32), dim3(256), 0, stream,
                       Wq, Wk, Wv, Wg, wthi, wtlo);
    hipLaunchKernelGGL(proj_mfma_kernel, dim3(25, 16), dim3(512), 0, stream,
                       xhi, xlo, wthi, wtlo, q, k_raw, v, gsig);
    hipLaunchKernelGGL(rope_conv_kernel, dim3(512, 10), dim3(256), 0, stream,
                       q, k_raw, qb, krb, qhi, qlo);
    hipLaunchKernelGGL(vtrans_kernel, dim3(64, 4, 2), dim3(256), 0, stream,
                       v, vT);
    hipLaunchKernelGGL(pool_kernel, dim3(64), dim3(256), 0, stream,
                       k_raw, v, wk_pool, wv_pool, pe, khi, klo, vcT);
    hipLaunchKernelGGL(cmp_mfma_kernel, dim3(128, 2), dim3(256), 0, stream,
                       qhi, qlo, khi, klo, vcT, o_cmp, sel);
    hipLaunchKernelGGL(slcswa_kernel, dim3(512, 2), dim3(256), 0, stream,
                       qb, krb, vT, sel, gsig, o_cmp, out);
}

// Round 11
// 145.006 us; speedup vs baseline: 1.6629x; 1.0355x over previous
//
#include <hip/hip_runtime.h>
#include <math.h>

#define NEGF  (-1e30f)
#define BIGF  (1000000.0f)
#define SCALE_ (0.08838834764831845f)   // 1/sqrt(128)
#define L2INV_ (0.20762050593046014f)   // log2(10000)/64
#define QT 8

typedef __attribute__((ext_vector_type(4))) float f32x4;
typedef __attribute__((ext_vector_type(8))) short short8;
typedef __attribute__((ext_vector_type(4))) short short4v;
typedef __attribute__((ext_vector_type(8))) _Float16 half8;

#define GLDS16(gp, lp) __builtin_amdgcn_global_load_lds( \
    (const __attribute__((address_space(1))) void*)(gp), \
    (__attribute__((address_space(3))) void*)(lp), 16, 0, 0)

__device__ __forceinline__ short bf16_of(float f) {
    union { float f; unsigned u; } x; x.f = f;
    unsigned r = x.u + 0x7fffu + ((x.u >> 16) & 1u);
    return (short)(r >> 16);
}
__device__ __forceinline__ float f32_of_bf16bits(unsigned u16) {
    union { unsigned u; float f; } x; x.u = u16 << 16;
    return x.f;
}
__device__ __forceinline__ short f16_of(float f) {
    _Float16 h = (_Float16)f;
    union { _Float16 h; short s; } u; u.h = h;
    return u.s;
}
__device__ __forceinline__ float f32_of_f16(short s) {
    union { _Float16 h; short s; } u; u.s = s;
    return (float)u.h;
}

// -------- Kernel 0a: x (fp32) -> xhi/xlo fp16 split ------------------------
__global__ __launch_bounds__(256) void xconv_kernel(
    const float* __restrict__ x, short* __restrict__ xhi, short* __restrict__ xlo)
{
    const int i = blockIdx.x * 1024 + threadIdx.x * 4;
    float4 f = *(const float4*)(x + i);
    short4v hi, lo;
    float fv[4] = {f.x, f.y, f.z, f.w};
    #pragma unroll
    for (int c = 0; c < 4; ++c) {
        short h = f16_of(fv[c]);
        hi[c] = h;
        lo[c] = f16_of(fv[c] - f32_of_f16(h));
    }
    *(short4v*)(xhi + i) = hi;
    *(short4v*)(xlo + i) = lo;
}

// -------- Kernel 0b: W's -> WT fp16 split, transposed [1600][1024] ---------
__global__ __launch_bounds__(256) void wconv_kernel(
    const float* __restrict__ Wq, const float* __restrict__ Wk,
    const float* __restrict__ Wv, const float* __restrict__ Wg,
    short* __restrict__ wthi, short* __restrict__ wtlo)
{
    __shared__ float tile[32][33];
    const int ct = blockIdx.x, kt = blockIdx.y;
    const int c = threadIdx.x & 31, r0 = threadIdx.x >> 5;
    #pragma unroll
    for (int rr = 0; rr < 32; rr += 8) {
        int k = kt * 32 + r0 + rr;
        int gc = ct * 32 + c;
        float val;
        if (gc < 1024)      val = Wq[k * 1024 + gc];
        else if (gc < 1280) val = Wk[k * 256 + gc - 1024];
        else if (gc < 1536) val = Wv[k * 256 + gc - 1280];
        else if (gc < 1560) val = Wg[k * 24 + gc - 1536];
        else                val = 0.f;
        tile[r0 + rr][c] = val;
    }
    __syncthreads();
    #pragma unroll
    for (int rr = 0; rr < 32; rr += 8) {
        int col = ct * 32 + r0 + rr;
        int k = kt * 32 + c;
        float val = tile[c][r0 + rr];
        short hi = f16_of(val);
        short lo = f16_of(val - f32_of_f16(hi));
        wthi[(size_t)col * 1024 + k] = hi;
        wtlo[(size_t)col * 1024 + k] = lo;
    }
}

// -------- Kernel 1: projections via split-fp16 MFMA, LDS-staged ------------
__global__ __launch_bounds__(512, 2) void proj_mfma_kernel(
    const short* __restrict__ xhi, const short* __restrict__ xlo,
    const short* __restrict__ wthi, const short* __restrict__ wtlo,
    float* __restrict__ q, float* __restrict__ k_raw,
    float* __restrict__ v, float* __restrict__ gsig)
{
    __shared__ __align__(16) short lds[24576];
    const int cb = blockIdx.x;
    const int tb = blockIdx.y;
    const int w = threadIdx.x >> 6;
    const int l = threadIdx.x & 63;
    const int l16 = l & 15, g4 = l >> 4;
    const int wm = w >> 1, wn = w & 1;
    const int row0 = tb * 128, col0 = cb * 64;

    const short* pAhi[2]; const short* pAlo[2];
    #pragma unroll
    for (int j = 0; j < 2; ++j) {
        int b = (2 * w + j) * 1024 + l * 16;
        int row = b >> 7;
        int kb = (b & 127) ^ ((row & 7) << 4);
        pAhi[j] = xhi + (size_t)(row0 + row) * 1024 + (kb >> 1);
        pAlo[j] = xlo + (size_t)(row0 + row) * 1024 + (kb >> 1);
    }
    const short* pBhi; const short* pBlo;
    {
        int b = w * 1024 + l * 16;
        int col = b >> 7;
        int kb = (b & 127) ^ ((col & 7) << 4);
        pBhi = wthi + (size_t)(col0 + col) * 1024 + (kb >> 1);
        pBlo = wtlo + (size_t)(col0 + col) * 1024 + (kb >> 1);
    }

    f32x4 acc[2][2];
    #pragma unroll
    for (int mt = 0; mt < 2; ++mt)
        #pragma unroll
        for (int nt = 0; nt < 2; ++nt) acc[mt][nt] = (f32x4)0.f;

    for (int k0 = 0; k0 < 1024; k0 += 64) {
        GLDS16(pAhi[0] + k0, &lds[(2 * w + 0) * 512]);
        GLDS16(pAhi[1] + k0, &lds[(2 * w + 1) * 512]);
        GLDS16(pAlo[0] + k0, &lds[8192 + (2 * w + 0) * 512]);
        GLDS16(pAlo[1] + k0, &lds[8192 + (2 * w + 1) * 512]);
        GLDS16(pBhi + k0,    &lds[16384 + w * 512]);
        GLDS16(pBlo + k0,    &lds[20480 + w * 512]);
        __syncthreads();
        #pragma unroll
        for (int ksub = 0; ksub < 2; ++ksub) {
            half8 ah[2], al[2], bh[2], bl[2];
            #pragma unroll
            for (int mt = 0; mt < 2; ++mt) {
                int row = wm * 32 + mt * 16 + l16;
                int kb = (ksub * 64 + g4 * 16) ^ ((row & 7) << 4);
                ah[mt] = *(const half8*)(const void*)&lds[row * 64 + (kb >> 1)];
                al[mt] = *(const half8*)(const void*)&lds[8192 + row * 64 + (kb >> 1)];
            }
            #pragma unroll
            for (int nt = 0; nt < 2; ++nt) {
                int col = wn * 32 + nt * 16 + l16;
                int kb = (ksub * 64 + g4 * 16) ^ ((col & 7) << 4);
                bh[nt] = *(const half8*)(const void*)&lds[16384 + col * 64 + (kb >> 1)];
                bl[nt] = *(const half8*)(const void*)&lds[20480 + col * 64 + (kb >> 1)];
            }
            #pragma unroll
            for (int mt = 0; mt < 2; ++mt)
                #pragma unroll
                for (int nt = 0; nt < 2; ++nt) {
                    acc[mt][nt] = __builtin_amdgcn_mfma_f32_16x16x32_f16(ah[mt], bh[nt], acc[mt][nt], 0, 0, 0);
                    acc[mt][nt] = __builtin_amdgcn_mfma_f32_16x16x32_f16(ah[mt], bl[nt], acc[mt][nt], 0, 0, 0);
                    acc[mt][nt] = __builtin_amdgcn_mfma_f32_16x16x32_f16(al[mt], bh[nt], acc[mt][nt], 0, 0, 0);
                }
        }
        __syncthreads();
    }
    #pragma unroll
    for (int mt = 0; mt < 2; ++mt) {
        #pragma unroll
        for (int r = 0; r < 4; ++r) {
            const int tt = row0 + wm * 32 + mt * 16 + g4 * 4 + r;
            #pragma unroll
            for (int nt = 0; nt < 2; ++nt) {
                const int cg = col0 + wn * 32 + nt * 16 + l16;
                const float val = acc[mt][nt][r];
                if (cg < 1024)      q[(size_t)tt * 1024 + cg] = val;
                else if (cg < 1280) k_raw[(size_t)tt * 256 + cg - 1024] = val;
                else if (cg < 1536) v[(size_t)tt * 256 + cg - 1280] = val;
                else if (cg < 1560) gsig[(size_t)tt * 24 + cg - 1536] = 1.0f / (1.0f + expf(-val));
            }
        }
    }
}

// ------ Kernel 2: RoPE on q (in place) + bf16 & fp16-split copies ----------
__global__ __launch_bounds__(256) void rope_conv_kernel(
    float* __restrict__ q, const float* __restrict__ k_raw,
    short* __restrict__ qb, short* __restrict__ krb,
    short* __restrict__ qhi, short* __restrict__ qlo)
{
    const int t = blockIdx.x * 4 + (threadIdx.x >> 6);
    const int h = blockIdx.y;
    const int i = threadIdx.x & 63;
    float inv = exp2f(-(float)i * L2INV_);
    float ang = (float)t * inv;
    float sn, cs;
    sincosf(ang, &sn, &cs);
    if (h < 8) {
        float* p = q + t * 1024 + h * 128;
        float x1 = p[i], x2 = p[i + 64];
        float r1 = x1 * cs - x2 * sn;
        float r2 = x1 * sn + x2 * cs;
        p[i] = r1; p[i + 64] = r2;
        const int o = t * 1024 + h * 128;
        qb[o + i]      = bf16_of(r1);
        qb[o + i + 64] = bf16_of(r2);
        short h1 = f16_of(r1), h2 = f16_of(r2);
        qhi[o + i] = h1;       qlo[o + i]      = f16_of(r1 - f32_of_f16(h1));
        qhi[o + i + 64] = h2;  qlo[o + i + 64] = f16_of(r2 - f32_of_f16(h2));
    } else {
        const float* s = k_raw + t * 256 + (h - 8) * 128;
        float x1 = s[i], x2 = s[i + 64];
        krb[t * 256 + (h - 8) * 128 + i]      = bf16_of(x1 * cs - x2 * sn);
        krb[t * 256 + (h - 8) * 128 + i + 64] = bf16_of(x1 * sn + x2 * cs);
    }
}

// ------ Kernel 2b: v (fp32 [s][kv][d]) -> vT bf16 [kv][d][s] ---------------
__global__ __launch_bounds__(256) void vtrans_kernel(
    const float* __restrict__ v, short* __restrict__ vT)
{
    __shared__ short tile[32][33];
    const int s0 = blockIdx.x * 32, d0 = blockIdx.y * 32, kv = blockIdx.z;
    const int c = threadIdx.x & 31, r0 = threadIdx.x >> 5;
    #pragma unroll
    for (int rr = 0; rr < 32; rr += 8) {
        int r = r0 + rr;
        tile[r][c] = bf16_of(v[((size_t)(s0 + r) * 2 + kv) * 128 + d0 + c]);
    }
    __syncthreads();
    #pragma unroll
    for (int rr = 0; rr < 32; rr += 8) {
        int r = r0 + rr;
        vT[((size_t)kv * 128 + d0 + r) * 2048 + s0 + c] = tile[c][r];
    }
}

// ------- Kernel 3: pool -> khi/klo (fp16 split, roped) + vcT (bf16 [kv][d][j])
__global__ __launch_bounds__(256) void pool_kernel(
    const float* __restrict__ k_raw, const float* __restrict__ v_raw,
    const float* __restrict__ wk_pool, const float* __restrict__ wv_pool,
    const float* __restrict__ pe, short* __restrict__ khi,
    short* __restrict__ klo, short* __restrict__ vcT)
{
    const int j = blockIdx.x;
    const int tid = threadIdx.x;
    const int kv = tid >> 7, d = tid & 127;
    float ak = 0.f, av = 0.f;
    for (int s = 0; s < 32; ++s) {
        float pev = pe[(kv * 32 + s) * 128 + d];
        float kk = k_raw[((j * 32 + s) * 2 + kv) * 128 + d] + pev;
        float vv = v_raw[((j * 32 + s) * 2 + kv) * 128 + d] + pev;
        ak += kk * wk_pool[kv * 32 + s];
        av += vv * wv_pool[kv * 32 + s];
    }
    __shared__ float sk[256];
    sk[tid] = ak;
    __syncthreads();
    int i = d & 63;
    float inv = exp2f(-(float)i * L2INV_);
    float ang = (float)(j * 32) * inv;
    float sn, cs; sincosf(ang, &sn, &cs);
    float x1 = sk[kv * 128 + i], x2 = sk[kv * 128 + i + 64];
    float outv = (d < 64) ? (x1 * cs - x2 * sn) : (x1 * sn + x2 * cs);
    short hi = f16_of(outv);
    khi[(j * 2 + kv) * 128 + d] = hi;
    klo[(j * 2 + kv) * 128 + d] = f16_of(outv - f32_of_f16(hi));
    vcT[((size_t)kv * 128 + d) * 64 + j] = bf16_of(av);
}

// ------- Kernel 4: compressed attention + pw + top-8, MFMA one-shot --------
__global__ __launch_bounds__(256) void cmp_mfma_kernel(
    const short* __restrict__ qhi, const short* __restrict__ qlo,
    const short* __restrict__ khi, const short* __restrict__ klo,
    const short* __restrict__ vcT, float* __restrict__ o_cmp,
    unsigned long long* __restrict__ sel_mask)
{
    const int t0 = blockIdx.x * 16;
    const int kv = blockIdx.y;
    const int g  = threadIdx.x >> 6;
    const int l  = threadIdx.x & 63;
    const int l16 = l & 15, g4 = l >> 4;
    __shared__ float pwpart[4][16][68];
    __shared__ __align__(16) short plds[4][16][72];
    const int tq = t0 + l16;

    half8 qfh[4], qfl[4];
    #pragma unroll
    for (int ks = 0; ks < 4; ++ks) {
        const size_t o = ((size_t)tq * 8 + kv * 4 + g) * 128 + ks * 32 + g4 * 8;
        qfh[ks] = *(const half8*)(const void*)(qhi + o);
        qfl[ks] = *(const half8*)(const void*)(qlo + o);
    }
    f32x4 sct[4];
    #pragma unroll
    for (int nt = 0; nt < 4; ++nt) {
        sct[nt] = (f32x4)0.f;
        #pragma unroll
        for (int ks = 0; ks < 4; ++ks) {
            const size_t o = ((size_t)(nt * 16 + l16) * 2 + kv) * 128 + ks * 32 + g4 * 8;
            half8 kfh = *(const half8*)(const void*)(khi + o);
            half8 kfl = *(const half8*)(const void*)(klo + o);
            sct[nt] = __builtin_amdgcn_mfma_f32_16x16x32_f16(kfh, qfh[ks], sct[nt], 0, 0, 0);
            sct[nt] = __builtin_amdgcn_mfma_f32_16x16x32_f16(kfh, qfl[ks], sct[nt], 0, 0, 0);
            sct[nt] = __builtin_amdgcn_mfma_f32_16x16x32_f16(kfl, qfh[ks], sct[nt], 0, 0, 0);
        }
    }
    float p[16];
    float mx = NEGF;
    #pragma unroll
    for (int nt = 0; nt < 4; ++nt)
        #pragma unroll
        for (int r = 0; r < 4; ++r) {
            const int j = nt * 16 + g4 * 4 + r;
            const bool vis = (tq >= j * 32 + 31);
            const float sv = vis ? sct[nt][r] * SCALE_ : NEGF;
            p[nt * 4 + r] = sv;
            mx = fmaxf(mx, sv);
        }
    mx = fmaxf(mx, __shfl_xor(mx, 16, 64));
    mx = fmaxf(mx, __shfl_xor(mx, 32, 64));
    float rs = 0.f;
    #pragma unroll
    for (int i = 0; i < 16; ++i) {
        float pv = (p[i] > -1e29f) ? __expf(p[i] - mx) : 0.f;
        p[i] = pv;
        rs += pv;
    }
    rs += __shfl_xor(rs, 16, 64);
    rs += __shfl_xor(rs, 32, 64);
    const float rl = (rs > 0.f) ? 1.0f / rs : 0.f;
    #pragma unroll
    for (int nt = 0; nt < 4; ++nt)
        #pragma unroll
        for (int r = 0; r < 4; ++r) {
            const int j = nt * 16 + g4 * 4 + r;
            pwpart[g][l16][j] = p[nt * 4 + r] * rl;
            plds[g][l16][j]   = bf16_of(p[nt * 4 + r]);
        }
    short8 pa0 = *(const short8*)(&plds[g][l16][g4 * 8]);
    short8 pa1 = *(const short8*)(&plds[g][l16][32 + g4 * 8]);
    f32x4 acc[8];
    #pragma unroll
    for (int dt = 0; dt < 8; ++dt) {
        const short* vr = vcT + ((size_t)kv * 128 + dt * 16 + l16) * 64;
        short8 vf0 = *(const short8*)(vr + g4 * 8);
        short8 vf1 = *(const short8*)(vr + 32 + g4 * 8);
        acc[dt] = (f32x4)0.f;
        acc[dt] = __builtin_amdgcn_mfma_f32_16x16x32_bf16(vf0, pa0, acc[dt], 0, 0, 0);
        acc[dt] = __builtin_amdgcn_mfma_f32_16x16x32_bf16(vf1, pa1, acc[dt], 0, 0, 0);
    }
    #pragma unroll
    for (int dt = 0; dt < 8; ++dt)
        #pragma unroll
        for (int r = 0; r < 4; ++r)
            o_cmp[(size_t)tq * 1024 + (kv * 4 + g) * 128 + dt * 16 + g4 * 4 + r] = acc[dt][r] * rl;
    __syncthreads();
    const int j = l;
    for (int qi = 0; qi < 4; ++qi) {
        const int qq = g * 4 + qi;
        const int tqq = t0 + qq;
        float pw = pwpart[0][qq][j] + pwpart[1][qq][j]
                 + pwpart[2][qq][j] + pwpart[3][qq][j];
        const int cur = tqq >> 5;
        const int curm1 = cur > 0 ? cur - 1 : 0;
        const bool forced = (j == 0) || (j == cur) || (j == curm1);
        const bool allowed = (j * 32 <= tqq);
        float sc = allowed ? (pw + (forced ? BIGF : 0.f)) : -1.0f;
        unsigned long long selm = 0ull;
        for (int it = 0; it < 8; ++it) {
            float bv = sc; int bi = j;
            #pragma unroll
            for (int off = 32; off >= 1; off >>= 1) {
                float ov = __shfl_xor(bv, off, 64);
                int   oi = __shfl_xor(bi, off, 64);
                if (ov > bv || (ov == bv && oi < bi)) { bv = ov; bi = oi; }
            }
            if (bv > -0.5f) selm |= (1ull << bi);
            if (j == bi) sc = -3e38f;
        }
        if (l == 0) sel_mask[(size_t)tqq * 2 + kv] = selm;
    }
}

// ------- Kernel 5: fused slc+swa, (q,g)-packed MFMA columns ----------------
// block = (8 queries, kv), 2 waves of 64. Wave w owns queries 4w..4w+3; MFMA
// col l16 = (query l16&3, head l16>>2) -> 100% column utilization. Unified
// entry list; K/V double-buffered LDS via global_load_lds, both-sides XOR
// swizzle (K: (row&7)<<4, V: ((row>>1)&3)<<4); defer-max (THR=8).
__global__ __launch_bounds__(128, 2) void slcswa_kernel(
    const short* __restrict__ qb, const short* __restrict__ krb,
    const short* __restrict__ vT, const unsigned long long* __restrict__ sel,
    const float* __restrict__ gsig, const float* __restrict__ o_cmp,
    float* __restrict__ out)
{
    const int t0 = blockIdx.x * QT;
    const int kv = blockIdx.y;
    const int w  = threadIdx.x >> 6;       // 0..1
    const int l  = threadIdx.x & 63;
    const int l16 = l & 15, g4 = l >> 4;
    const int qq = 4 * w + (l16 & 3);      // query index within block
    const int gg = l16 >> 2;               // head g 0..3
    __shared__ __align__(16) short kbuf[2][4096];   // 32 keys x 256B
    __shared__ __align__(16) short vbuf[2][4096];   // 128 d x 64B
    __shared__ __align__(16) short plds[2][16][40];
    __shared__ int list_s0[80];
    __shared__ unsigned char list_md[80];
    __shared__ unsigned long long qm[QT];
    __shared__ int ne_s, nslc_s;

    if (threadIdx.x < QT) qm[threadIdx.x] = sel[(size_t)(t0 + threadIdx.x) * 2 + kv];
    __syncthreads();
    if (threadIdx.x == 0) {
        unsigned long long u = 0ull;
        #pragma unroll
        for (int i = 0; i < QT; ++i) u |= qm[i];
        int n = 0;
        while (u) { int j = __ffsll((long long)u) - 1; list_s0[n] = j * 32; list_md[n] = 0; ++n; u &= u - 1; }
        nslc_s = n;
        int sLo = (t0 >= 256) ? ((t0 - 256) & ~31) : 0;
        for (int s0 = sLo; s0 <= t0 + QT - 1; s0 += 32) { list_s0[n] = s0; list_md[n] = 1; ++n; }
        ne_s = n;
    }
    __syncthreads();
    const int ne = ne_s, nslc = nslc_s;

    const int tq = t0 + qq;
    const unsigned long long myqm = qm[qq];
    short8 qf[4];
    #pragma unroll
    for (int ks = 0; ks < 4; ++ks)
        qf[ks] = *(const short8*)(qb + ((size_t)tq * 8 + kv * 4 + gg) * 128 + ks * 32 + g4 * 8);

    // staging: 128 threads x 16B x 4 passes per tile (8KB each).
    // LDS dest linear (wave-uniform base + lane*16); global src pre-swizzled.
    #define STAGE_KV(buf, s0v)                                                    \
    {                                                                             \
        _Pragma("unroll")                                                         \
        for (int ps = 0; ps < 4; ++ps) {                                          \
            int off = ps * 2048 + w * 1024 + (l << 4);                            \
            int row = off >> 8, col = off & 255;                                  \
            int cs = col ^ ((row & 7) << 4);                                      \
            const short* src = krb + (((size_t)((s0v) + row) * 2 + kv) << 7) + (cs >> 1); \
            GLDS16(src, &kbuf[buf][(ps * 2048 + w * 1024) >> 1]);                 \
        }                                                                         \
        _Pragma("unroll")                                                         \
        for (int ps = 0; ps < 4; ++ps) {                                          \
            int off = ps * 2048 + w * 1024 + (l << 4);                            \
            int row = off >> 6, col = off & 63;                                   \
            int cs = col ^ (((row >> 1) & 3) << 4);                               \
            const short* src = vT + (size_t)(kv * 128 + row) * 2048 + (s0v) + (cs >> 1); \
            GLDS16(src, &vbuf[buf][(ps * 2048 + w * 1024) >> 1]);                 \
        }                                                                         \
    }

    f32x4 acc[8];
    #pragma unroll
    for (int dt = 0; dt < 8; ++dt) acc[dt] = (f32x4)0.f;
    float m_r = NEGF, l_r = 0.f;
    unsigned oslc_pk[16];

    STAGE_KV(0, list_s0[0]);
    __syncthreads();

    for (int e = 0; e < ne; ++e) {
        const int s0 = list_s0[e];
        const int md = list_md[e];
        const int cur = e & 1;
        if (e + 1 < ne) STAGE_KV(cur ^ 1, list_s0[e + 1]);

        // QK^T (swapped): S^T[key][col=(q,g)]
        f32x4 sct[2];
        sct[0] = (f32x4)0.f; sct[1] = (f32x4)0.f;
        #pragma unroll
        for (int nt = 0; nt < 2; ++nt) {
            const int row = nt * 16 + l16;
            short8 kf[4];
            #pragma unroll
            for (int ks = 0; ks < 4; ++ks)
                kf[ks] = *(const short8*)&kbuf[cur][row * 128 + ((((ks * 64 + g4 * 16) ^ ((row & 7) << 4))) >> 1)];
            #pragma unroll
            for (int ks = 0; ks < 4; ++ks)
                sct[nt] = __builtin_amdgcn_mfma_f32_16x16x32_bf16(kf[ks], qf[ks], sct[nt], 0, 0, 0);
        }
        const bool inm = md ? true : ((myqm >> (s0 >> 5)) & 1ull);
        float p[8];
        float mx = NEGF;
        #pragma unroll
        for (int nt = 0; nt < 2; ++nt)
            #pragma unroll
            for (int r = 0; r < 4; ++r) {
                const int key = s0 + nt * 16 + g4 * 4 + r;
                const bool vv = md ? ((key <= tq) && (key >= tq - 256))
                                   : (inm && (key <= tq));
                const float sv = vv ? sct[nt][r] * SCALE_ : NEGF;
                p[nt * 4 + r] = sv;
                mx = fmaxf(mx, sv);
            }
        mx = fmaxf(mx, __shfl_xor(mx, 16, 64));
        mx = fmaxf(mx, __shfl_xor(mx, 32, 64));
        // defer-max (T13): skip rescale unless some lane's max grew > 8
        if (!__all(mx <= m_r + 8.0f)) {
            const float mnew = fmaxf(m_r, mx);
            const float alx = __expf(m_r - mnew);
            l_r *= alx;
            m_r = mnew;
            #pragma unroll
            for (int dt = 0; dt < 8; ++dt) acc[dt] *= alx;
        }
        float rs = 0.f;
        #pragma unroll
        for (int i = 0; i < 8; ++i) { float pv = __expf(p[i] - m_r); p[i] = pv; rs += pv; }
        rs += __shfl_xor(rs, 16, 64);
        rs += __shfl_xor(rs, 32, 64);
        l_r += rs;
        short4v pk0, pk1;
        #pragma unroll
        for (int r = 0; r < 4; ++r) { pk0[r] = bf16_of(p[r]); pk1[r] = bf16_of(p[4 + r]); }
        *(short4v*)&plds[w][l16][g4 * 4]      = pk0;
        *(short4v*)&plds[w][l16][16 + g4 * 4] = pk1;
        short8 pa = *(const short8*)(&plds[w][l16][g4 * 8]);
        #pragma unroll
        for (int dt = 0; dt < 8; ++dt) {
            const int row = dt * 16 + l16;
            short8 vf = *(const short8*)&vbuf[cur][row * 32 + (((g4 * 16) ^ (((row >> 1) & 3) << 4)) >> 1)];
            acc[dt] = __builtin_amdgcn_mfma_f32_16x16x32_bf16(vf, pa, acc[dt], 0, 0, 0);
        }
        if (e == nslc - 1) {
            const float rl = 1.0f / l_r;
            #pragma unroll
            for (int dt = 0; dt < 8; ++dt) {
                oslc_pk[dt * 2 + 0] = ((unsigned)(unsigned short)bf16_of(acc[dt][0] * rl))
                                    | (((unsigned)(unsigned short)bf16_of(acc[dt][1] * rl)) << 16);
                oslc_pk[dt * 2 + 1] = ((unsigned)(unsigned short)bf16_of(acc[dt][2] * rl))
                                    | (((unsigned)(unsigned short)bf16_of(acc[dt][3] * rl)) << 16);
                acc[dt] = (f32x4)0.f;
            }
            m_r = NEGF; l_r = 0.f;
        }
        __syncthreads();
    }

    // ---- gated combine: every lane owns 8x float4 of output row (tq, gg) --
    {
        const float rlw = 1.0f / l_r;
        const float gc = gsig[(size_t)tq * 24 + kv * 12 + gg * 3 + 0];
        const float gs = gsig[(size_t)tq * 24 + kv * 12 + gg * 3 + 1];
        const float gw = gsig[(size_t)tq * 24 + kv * 12 + gg * 3 + 2];
        const size_t base = (size_t)tq * 1024 + (kv * 4 + gg) * 128;
        #pragma unroll
        for (int dt = 0; dt < 8; ++dt) {
            const size_t idx = base + dt * 16 + g4 * 4;
            float4 oc = *(const float4*)(o_cmp + idx);
            const unsigned pkA = oslc_pk[dt * 2 + 0];
            const unsigned pkB = oslc_pk[dt * 2 + 1];
            float4 o4;
            o4.x = gc * oc.x + gs * f32_of_bf16bits(pkA & 0xffffu)  + gw * acc[dt][0] * rlw;
            o4.y = gc * oc.y + gs * f32_of_bf16bits(pkA >> 16)      + gw * acc[dt][1] * rlw;
            o4.z = gc * oc.z + gs * f32_of_bf16bits(pkB & 0xffffu)  + gw * acc[dt][2] * rlw;
            o4.w = gc * oc.w + gs * f32_of_bf16bits(pkB >> 16)      + gw * acc[dt][3] * rlw;
            *(float4*)(out + idx) = o4;
        }
    }
}

extern "C" void kernel_launch(void* const* d_in, const int* in_sizes, int n_in,
                              void* d_out, int out_size, void* d_ws, size_t ws_size,
                              hipStream_t stream)
{
    const float* x       = (const float*)d_in[0];
    const float* Wq      = (const float*)d_in[1];
    const float* Wk      = (const float*)d_in[2];
    const float* Wv      = (const float*)d_in[3];
    const float* Wg      = (const float*)d_in[4];
    const float* wk_pool = (const float*)d_in[5];
    const float* wv_pool = (const float*)d_in[6];
    const float* pe      = (const float*)d_in[7];
    float* out = (float*)d_out;
    float* ws  = (float*)d_ws;

    // ---- workspace layout (floats); total ~36.1 MB ----
    float* q     = ws;                         // 2,097,152
    float* k_raw = q + 2097152;                //   524,288
    float* v     = k_raw + 524288;             //   524,288
    float* gsig  = v + 524288;                 //    49,152
    unsigned long long* sel = (unsigned long long*)(gsig + 49152); // 8,192 f
    float* o_cmp = (float*)sel + 8192;         // 2,097,152
    short* xhi   = (short*)o_cmp;              // alias o_cmp (dead before cmp writes)
    short* xlo   = xhi + 2097152;
    short* qb    = (short*)(o_cmp + 2097152);  // 2,097,152 sh
    short* krb   = qb + 2097152;               //   524,288 sh
    short* vT    = krb + 524288;               //   524,288 sh
    short* khi   = vT + 524288;                //    16,384 sh  (in wtlo tail pad)
    short* klo   = khi + 16384;                //    16,384 sh
    short* vcT   = klo + 16384;                //    16,384 sh
    short* wthi  = qb;                         // alias qb.. (dead before rope/pool)
    short* wtlo  = wthi + 1638400;             // spans krb/vT/pad
    short* qhi   = qb + 3276800;               // 2,097,152 sh (after wtlo end)
    short* qlo   = qhi + 2097152;              // 2,097,152 sh

    hipLaunchKernelGGL(xconv_kernel, dim3(2048), dim3(256), 0, stream, x, xhi, xlo);
    hipLaunchKernelGGL(wconv_kernel, dim3(50, 32), dim3(256), 0, stream,
                       Wq, Wk, Wv, Wg, wthi, wtlo);
    hipLaunchKernelGGL(proj_mfma_kernel, dim3(25, 16), dim3(512), 0, stream,
                       xhi, xlo, wthi, wtlo, q, k_raw, v, gsig);
    hipLaunchKernelGGL(rope_conv_kernel, dim3(512, 10), dim3(256), 0, stream,
                       q, k_raw, qb, krb, qhi, qlo);
    hipLaunchKernelGGL(vtrans_kernel, dim3(64, 4, 2), dim3(256), 0, stream,
                       v, vT);
    hipLaunchKernelGGL(pool_kernel, dim3(64), dim3(256), 0, stream,
                       k_raw, v, wk_pool, wv_pool, pe, khi, klo, vcT);
    hipLaunchKernelGGL(cmp_mfma_kernel, dim3(128, 2), dim3(256), 0, stream,
                       qhi, qlo, khi, klo, vcT, o_cmp, sel);
    hipLaunchKernelGGL(slcswa_kernel, dim3(256, 2), dim3(128), 0, stream,
                       qb, krb, vT, sel, gsig, o_cmp, out);
}